// Round 1
// baseline (3809.922 us; speedup 1.0000x reference)
//
#include <hip/hip_runtime.h>

#define QLEN 2048
#define BSZ  2
#define NH   12
#define DH   64
#define DM   768
#define HID  2304
#define NKT  32          // QLEN/64 row tiles
#define SCALE 0.125f

static __device__ __forceinline__ float dot4(float4 a, float4 b) {
  return a.x*b.x + a.y*b.y + a.z*b.z + a.w*b.w;
}

// ---------------------------------------------------------------------------
// Kernel 1: QKV projection.  C[r][h] = sum_m w[r][m] * qkv_w[h][m]
// r = i*BSZ+b (M=4096), h in [0,2304).  Scatter into Q/K/V laid out [b][n][i][d].
// 64x64 tile, 16x16 threads, 4x4 micro-tile, K-step 32, LDS transposed [k][m].
// ---------------------------------------------------------------------------
__global__ __launch_bounds__(256)
void qkv_gemm(const float* __restrict__ A, const float* __restrict__ B,
              float* __restrict__ Qo, float* __restrict__ Ko, float* __restrict__ Vo) {
  __shared__ __align__(16) float As[32][68];
  __shared__ __align__(16) float Bs[32][68];
  const int bn = blockIdx.x;      // N tiles: 36
  const int bm = blockIdx.y;      // M tiles: 64
  const int tx = threadIdx.x, ty = threadIdx.y;
  const int t  = ty*16 + tx;
  const int lr = t >> 3;          // 0..31
  const int lc = (t & 7) << 2;    // 0..28 step 4
  float acc[4][4] = {};
  for (int kk = 0; kk < DM; kk += 32) {
    const float4 a0 = *(const float4*)&A[(size_t)(bm*64 + lr     )*DM + kk + lc];
    const float4 a1 = *(const float4*)&A[(size_t)(bm*64 + lr + 32)*DM + kk + lc];
    const float4 b0 = *(const float4*)&B[(size_t)(bn*64 + lr     )*DM + kk + lc];
    const float4 b1 = *(const float4*)&B[(size_t)(bn*64 + lr + 32)*DM + kk + lc];
    __syncthreads();
    As[lc+0][lr] = a0.x; As[lc+1][lr] = a0.y; As[lc+2][lr] = a0.z; As[lc+3][lr] = a0.w;
    As[lc+0][lr+32] = a1.x; As[lc+1][lr+32] = a1.y; As[lc+2][lr+32] = a1.z; As[lc+3][lr+32] = a1.w;
    Bs[lc+0][lr] = b0.x; Bs[lc+1][lr] = b0.y; Bs[lc+2][lr] = b0.z; Bs[lc+3][lr] = b0.w;
    Bs[lc+0][lr+32] = b1.x; Bs[lc+1][lr+32] = b1.y; Bs[lc+2][lr+32] = b1.z; Bs[lc+3][lr+32] = b1.w;
    __syncthreads();
    #pragma unroll
    for (int k = 0; k < 32; ++k) {
      const float4 a4 = *(const float4*)&As[k][ty<<2];
      const float4 b4 = *(const float4*)&Bs[k][tx<<2];
      const float aa[4] = {a4.x, a4.y, a4.z, a4.w};
      const float bb[4] = {b4.x, b4.y, b4.z, b4.w};
      #pragma unroll
      for (int mi = 0; mi < 4; ++mi)
        #pragma unroll
        for (int ni = 0; ni < 4; ++ni)
          acc[mi][ni] += aa[mi]*bb[ni];
    }
  }
  // epilogue: scatter.  One 64-wide col tile never straddles q/k/v parts (64|768).
  const int h0   = bn*64 + (tx<<2);
  const int part = h0 / DM;
  const int rem  = h0 - part*DM;
  const int n    = rem >> 6;
  const int d0   = rem & 63;
  float* dstP = (part == 0) ? Qo : ((part == 1) ? Ko : Vo);
  #pragma unroll
  for (int mi = 0; mi < 4; ++mi) {
    const int r = bm*64 + (ty<<2) + mi;
    const int i = r >> 1, b = r & 1;
    const float4 v = make_float4(acc[mi][0], acc[mi][1], acc[mi][2], acc[mi][3]);
    *(float4*)&dstP[((size_t)(b*NH + n)*QLEN + i)*DH + d0] = v;
  }
}

// ---------------------------------------------------------------------------
// Kernel 2: KB[b,n,j] = dot(r_w_bias[n], K[b,n,j,:])   (wave per row)
// ---------------------------------------------------------------------------
__global__ __launch_bounds__(256)
void kbias_kernel(const float* __restrict__ K, const float* __restrict__ rwb,
                  float* __restrict__ KB) {
  const int wv = threadIdx.x >> 6, lane = threadIdx.x & 63;
  const int row = blockIdx.x*4 + wv;             // (b*NH+n)*QLEN + j
  const int n = (row / QLEN) % NH;
  float v = K[(size_t)row*DH + lane] * rwb[n*DH + lane];
  #pragma unroll
  for (int o = 32; o > 0; o >>= 1) v += __shfl_xor(v, o, 64);
  if (lane == 0) KB[row] = v;
}

// ---------------------------------------------------------------------------
// Kernel 3: flash attention with rel-shift term.
// grid = (row_tile it in [0,32), bn in [0,24)).  block = 256 = 4 waves.
// wave w handles rows w*16..w*16+15; lanes = 64 keys of the current key tile.
// score = (q.k + KB[j] + q.rel[2047+j-i] + rbias[2047+j-i]) * SCALE, causal.
// LDS tiles swizzled: element (row,c) stored at row*64 + (c ^ ((row&7)<<2)).
// ---------------------------------------------------------------------------
__global__ __launch_bounds__(256)
void attn_kernel(const float* __restrict__ Q, const float* __restrict__ K,
                 const float* __restrict__ V, const float* __restrict__ KB,
                 const float* __restrict__ remb, const float* __restrict__ rbias,
                 float* __restrict__ AV) {
  __shared__ __align__(16) float Qs[64*64];
  __shared__ __align__(16) float Ks[64*64];
  __shared__ __align__(16) float Vs[64*64];
  __shared__ __align__(16) float RELs[128*64];
  __shared__ float rb_s[128];
  __shared__ __align__(16) float Pw[4][2][64];
  const int it  = blockIdx.x;
  const int bn  = blockIdx.y;
  const int n   = bn % NH;
  const int tid = threadIdx.x;
  const int wv = tid >> 6, lane = tid & 63;
  const size_t base = (size_t)bn * QLEN * DH;

  // stage Q tile (once)
  {
    const int rr  = tid >> 2;
    const int seg = (tid & 3) << 4;
    #pragma unroll
    for (int ii = 0; ii < 4; ++ii) {
      const int c = seg + (ii << 2);
      const float4 v = *(const float4*)&Q[base + (size_t)(it*64 + rr)*DH + c];
      *(float4*)&Qs[rr*64 + (c ^ ((rr & 7) << 2))] = v;
    }
  }
  float accr[16], mrow[16], lrow[16];
  #pragma unroll
  for (int r = 0; r < 16; ++r) { accr[r] = 0.f; mrow[r] = -3.0e38f; lrow[r] = 0.f; }

  for (int jt = 0; jt <= it; ++jt) {
    __syncthreads();  // previous tile's readers done before overwrite
    {
      const int rr  = tid >> 2;
      const int seg = (tid & 3) << 4;
      #pragma unroll
      for (int ii = 0; ii < 4; ++ii) {
        const int c = seg + (ii << 2);
        const float4 kv = *(const float4*)&K[base + (size_t)(jt*64 + rr)*DH + c];
        *(float4*)&Ks[rr*64 + (c ^ ((rr & 7) << 2))] = kv;
        const float4 vv = *(const float4*)&V[base + (size_t)(jt*64 + rr)*DH + c];
        *(float4*)&Vs[rr*64 + (c ^ ((rr & 7) << 2))] = vv;
      }
    }
    const int r0g = 1984 - 64*(it - jt);    // global rel row base; rloc = 63+lane-i_loc
    {
      const int rl    = tid >> 1;           // 0..127
      const int halfc = (tid & 1) << 5;     // 0 or 32
      const int g = r0g + rl;
      #pragma unroll
      for (int ii = 0; ii < 8; ++ii) {
        const int c = halfc + (ii << 2);
        const float4 rv = (g < QLEN) ? *(const float4*)&remb[((size_t)g*NH + n)*DH + c]
                                     : make_float4(0.f, 0.f, 0.f, 0.f);
        *(float4*)&RELs[rl*64 + (c ^ ((rl & 7) << 2))] = rv;
      }
      if ((tid & 1) == 0) rb_s[rl] = (g < QLEN) ? rbias[g*NH + n] : 0.f;
    }
    __syncthreads();

    const float kbj = KB[bn*QLEN + jt*64 + lane];
    const int   jg  = jt*64 + lane;

    #pragma unroll
    for (int rp = 0; rp < 8; ++rp) {
      const int il0 = wv*16 + rp*2, il1 = il0 + 1;
      const int gi0 = it*64 + il0,  gi1 = gi0 + 1;
      const int rl0 = 63 + lane - il0, rl1 = rl0 - 1;
      float s0a = 0.f, s0b = 0.f, s1a = 0.f, s1b = 0.f;
      #pragma unroll
      for (int d4 = 0; d4 < 16; ++d4) {
        const int c = d4 << 2;
        const float4 k4 = *(const float4*)&Ks[lane*64 + (c ^ ((lane & 7) << 2))];
        const float4 q0 = *(const float4*)&Qs[il0*64 + (c ^ ((il0 & 7) << 2))];
        const float4 q1 = *(const float4*)&Qs[il1*64 + (c ^ ((il1 & 7) << 2))];
        const float4 e0 = *(const float4*)&RELs[rl0*64 + (c ^ ((rl0 & 7) << 2))];
        const float4 e1 = *(const float4*)&RELs[rl1*64 + (c ^ ((rl1 & 7) << 2))];
        s0a += dot4(q0, k4); s0b += dot4(q0, e0);
        s1a += dot4(q1, k4); s1b += dot4(q1, e1);
      }
      float s0 = (s0a + s0b + kbj + rb_s[rl0]) * SCALE;
      float s1 = (s1a + s1b + kbj + rb_s[rl1]) * SCALE;
      if (jg > gi0) s0 = -3.0e38f;
      if (jg > gi1) s1 = -3.0e38f;
      float t0 = s0, t1 = s1;
      #pragma unroll
      for (int o = 32; o > 0; o >>= 1) {
        t0 = fmaxf(t0, __shfl_xor(t0, o, 64));
        t1 = fmaxf(t1, __shfl_xor(t1, o, 64));
      }
      const float m0 = fmaxf(mrow[rp*2],     t0);
      const float m1 = fmaxf(mrow[rp*2 + 1], t1);
      const float al0 = __expf(mrow[rp*2]     - m0);
      const float al1 = __expf(mrow[rp*2 + 1] - m1);
      const float p0 = __expf(s0 - m0);
      const float p1 = __expf(s1 - m1);
      float u0 = p0, u1 = p1;
      #pragma unroll
      for (int o = 32; o > 0; o >>= 1) {
        u0 += __shfl_xor(u0, o, 64);
        u1 += __shfl_xor(u1, o, 64);
      }
      lrow[rp*2]     = lrow[rp*2]    *al0 + u0;
      lrow[rp*2 + 1] = lrow[rp*2 + 1]*al1 + u1;
      mrow[rp*2] = m0; mrow[rp*2 + 1] = m1;
      Pw[wv][0][lane] = p0;
      Pw[wv][1][lane] = p1;
      float a0 = accr[rp*2]*al0, a1 = accr[rp*2 + 1]*al1;
      // same-wave LDS RAW: compiler orders ds ops through memory dependence
      #pragma unroll
      for (int j4 = 0; j4 < 16; ++j4) {
        const float4 p04 = *(const float4*)&Pw[wv][0][j4 << 2];
        const float4 p14 = *(const float4*)&Pw[wv][1][j4 << 2];
        const float pa[4] = {p04.x, p04.y, p04.z, p04.w};
        const float pb[4] = {p14.x, p14.y, p14.z, p14.w};
        #pragma unroll
        for (int e = 0; e < 4; ++e) {
          const int jj = (j4 << 2) + e;
          const float vvv = Vs[jj*64 + (lane ^ ((jj & 7) << 2))];
          a0 += pa[e]*vvv; a1 += pb[e]*vvv;
        }
      }
      accr[rp*2] = a0; accr[rp*2 + 1] = a1;
    }
  }
  #pragma unroll
  for (int r = 0; r < 16; ++r) {
    const int gi = it*64 + wv*16 + r;
    AV[base + (size_t)gi*DH + lane] = accr[r] / lrow[r];
  }
}

// ---------------------------------------------------------------------------
// Kernel 4: O-projection GEMM.  AO[r][m] = sum_h AV[r][h] * o_w[m][h]
// AV gathered from [b][n][i][d] layout.
// ---------------------------------------------------------------------------
__global__ __launch_bounds__(256)
void oproj_gemm(const float* __restrict__ AVp, const float* __restrict__ B,
                float* __restrict__ AO) {
  __shared__ __align__(16) float As[32][68];
  __shared__ __align__(16) float Bs[32][68];
  const int bn = blockIdx.x;      // 12
  const int bm = blockIdx.y;      // 64
  const int tx = threadIdx.x, ty = threadIdx.y;
  const int t  = ty*16 + tx;
  const int lr = t >> 3;
  const int lc = (t & 7) << 2;
  float acc[4][4] = {};
  for (int kk = 0; kk < DM; kk += 32) {
    const int h = kk + lc, hn = h >> 6, hd = h & 63;
    const int r0r = bm*64 + lr, r1r = r0r + 32;
    const int i0 = r0r >> 1, b0v = r0r & 1;
    const int i1 = r1r >> 1, b1v = r1r & 1;
    const float4 a0 = *(const float4*)&AVp[((size_t)(b0v*NH + hn)*QLEN + i0)*DH + hd];
    const float4 a1 = *(const float4*)&AVp[((size_t)(b1v*NH + hn)*QLEN + i1)*DH + hd];
    const float4 b0 = *(const float4*)&B[(size_t)(bn*64 + lr     )*DM + kk + lc];
    const float4 b1 = *(const float4*)&B[(size_t)(bn*64 + lr + 32)*DM + kk + lc];
    __syncthreads();
    As[lc+0][lr] = a0.x; As[lc+1][lr] = a0.y; As[lc+2][lr] = a0.z; As[lc+3][lr] = a0.w;
    As[lc+0][lr+32] = a1.x; As[lc+1][lr+32] = a1.y; As[lc+2][lr+32] = a1.z; As[lc+3][lr+32] = a1.w;
    Bs[lc+0][lr] = b0.x; Bs[lc+1][lr] = b0.y; Bs[lc+2][lr] = b0.z; Bs[lc+3][lr] = b0.w;
    Bs[lc+0][lr+32] = b1.x; Bs[lc+1][lr+32] = b1.y; Bs[lc+2][lr+32] = b1.z; Bs[lc+3][lr+32] = b1.w;
    __syncthreads();
    #pragma unroll
    for (int k = 0; k < 32; ++k) {
      const float4 a4 = *(const float4*)&As[k][ty<<2];
      const float4 b4 = *(const float4*)&Bs[k][tx<<2];
      const float aa[4] = {a4.x, a4.y, a4.z, a4.w};
      const float bb[4] = {b4.x, b4.y, b4.z, b4.w};
      #pragma unroll
      for (int mi = 0; mi < 4; ++mi)
        #pragma unroll
        for (int ni = 0; ni < 4; ++ni)
          acc[mi][ni] += aa[mi]*bb[ni];
    }
  }
  #pragma unroll
  for (int mi = 0; mi < 4; ++mi) {
    const int r = bm*64 + (ty<<2) + mi;
    const float4 v = make_float4(acc[mi][0], acc[mi][1], acc[mi][2], acc[mi][3]);
    *(float4*)&AO[(size_t)r*DM + bn*64 + (tx<<2)] = v;
  }
}

// ---------------------------------------------------------------------------
// Kernel 5: residual + LayerNorm.  block per row r, 3 elems/thread.
// ---------------------------------------------------------------------------
__global__ __launch_bounds__(256)
void ln_kernel(const float* __restrict__ AO, const float* __restrict__ W,
               const float* __restrict__ gamma, const float* __restrict__ beta,
               float* __restrict__ out) {
  const int r = blockIdx.x;
  const int tid = threadIdx.x;
  const int wv = tid >> 6, lane = tid & 63;
  float x[3];
  #pragma unroll
  for (int q = 0; q < 3; ++q) {
    const int m = tid + q*256;
    x[q] = AO[(size_t)r*DM + m] + W[(size_t)r*DM + m];
  }
  float s1 = x[0] + x[1] + x[2];
  float s2 = x[0]*x[0] + x[1]*x[1] + x[2]*x[2];
  #pragma unroll
  for (int o = 32; o > 0; o >>= 1) { s1 += __shfl_xor(s1, o, 64); s2 += __shfl_xor(s2, o, 64); }
  __shared__ float a1[4], a2[4];
  if (lane == 0) { a1[wv] = s1; a2[wv] = s2; }
  __syncthreads();
  s1 = a1[0] + a1[1] + a1[2] + a1[3];
  s2 = a2[0] + a2[1] + a2[2] + a2[3];
  const float mu  = s1 * (1.0f/DM);
  const float var = s2 * (1.0f/DM) - mu*mu;
  const float rs  = rsqrtf(var + 1e-5f);
  #pragma unroll
  for (int q = 0; q < 3; ++q) {
    const int m = tid + q*256;
    out[(size_t)r*DM + m] = (x[q] - mu)*rs*gamma[m] + beta[m];
  }
}

// ---------------------------------------------------------------------------
extern "C" void kernel_launch(void* const* d_in, const int* in_sizes, int n_in,
                              void* d_out, int out_size, void* d_ws, size_t ws_size,
                              hipStream_t stream) {
  const float* w      = (const float*)d_in[0];
  const float* r_emb  = (const float*)d_in[1];
  const float* r_wb   = (const float*)d_in[2];
  const float* r_bias = (const float*)d_in[3];
  const float* qkv_w  = (const float*)d_in[4];
  const float* o_w    = (const float*)d_in[5];
  const float* ln_g   = (const float*)d_in[6];
  const float* ln_b   = (const float*)d_in[7];
  // d_in[8] = attn_mask: pure causal triu(k=1), recomputed analytically in-kernel.
  float* out = (float*)d_out;
  float* ws  = (float*)d_ws;

  const size_t QS = (size_t)BSZ*NH*QLEN*DH;   // 3,145,728 floats
  float* Qb  = ws;
  float* Kb  = ws + QS;
  float* Vb  = ws + 2*QS;
  float* AVb = ws + 3*QS;
  float* KBb = ws + 4*QS;                     // + 49,152 floats  (~48.2 MB total)
  float* AOb = Qb;                            // reuse Q slot after attention

  qkv_gemm<<<dim3(HID/64, (QLEN*BSZ)/64), dim3(16,16), 0, stream>>>(w, qkv_w, Qb, Kb, Vb);
  kbias_kernel<<<dim3(BSZ*NH*QLEN/4), dim3(256), 0, stream>>>(Kb, r_wb, KBb);
  attn_kernel<<<dim3(NKT, BSZ*NH), dim3(256), 0, stream>>>(Qb, Kb, Vb, KBb, r_emb, r_bias, AVb);
  oproj_gemm<<<dim3(DM/64, (QLEN*BSZ)/64), dim3(16,16), 0, stream>>>(AVb, o_w, AOb);
  ln_kernel<<<dim3(QLEN*BSZ), dim3(256), 0, stream>>>(AOb, w, ln_g, ln_b, out);
}

// Round 2
// 581.851 us; speedup vs baseline: 6.5479x; 6.5479x over previous
//
#include <hip/hip_runtime.h>

#define QLEN 2048
#define BSZ  2
#define NH   12
#define DH   64
#define DM   768
#define HID  2304
#define NKT  32          // QLEN/64 row tiles
#define SCALE 0.125f
#define RELROWS 2176     // 2048 + 128 zero pad
#define PADT 84          // T strip row stride (f32)
#define PADP 72          // P tile row stride (bf16)

typedef __attribute__((ext_vector_type(8))) short short8;
typedef __attribute__((ext_vector_type(4))) float f32x4;

static __device__ __forceinline__ unsigned short f2bf(float x) {
  unsigned u = __float_as_uint(x);
  return (unsigned short)((u + 0x7FFFu + ((u >> 16) & 1u)) >> 16);
}
static __device__ __forceinline__ float bf2f(unsigned short h) {
  return __uint_as_float(((unsigned)h) << 16);
}

// ---------------------------------------------------------------------------
// Kernel 1: QKV projection (f32 GEMM, unchanged math).  Epilogue writes
// Q,K as bf16 [bn][i][d] and V as f32 [bn][j][d].
// ---------------------------------------------------------------------------
__global__ __launch_bounds__(256)
void qkv_gemm(const float* __restrict__ A, const float* __restrict__ B,
              unsigned short* __restrict__ Qo, unsigned short* __restrict__ Ko,
              float* __restrict__ Vo) {
  __shared__ __align__(16) float As[32][68];
  __shared__ __align__(16) float Bs[32][68];
  const int bn = blockIdx.x;      // 36
  const int bm = blockIdx.y;      // 64
  const int tx = threadIdx.x, ty = threadIdx.y;
  const int t  = ty*16 + tx;
  const int lr = t >> 3;
  const int lc = (t & 7) << 2;
  float acc[4][4] = {};
  for (int kk = 0; kk < DM; kk += 32) {
    const float4 a0 = *(const float4*)&A[(size_t)(bm*64 + lr     )*DM + kk + lc];
    const float4 a1 = *(const float4*)&A[(size_t)(bm*64 + lr + 32)*DM + kk + lc];
    const float4 b0 = *(const float4*)&B[(size_t)(bn*64 + lr     )*DM + kk + lc];
    const float4 b1 = *(const float4*)&B[(size_t)(bn*64 + lr + 32)*DM + kk + lc];
    __syncthreads();
    As[lc+0][lr] = a0.x; As[lc+1][lr] = a0.y; As[lc+2][lr] = a0.z; As[lc+3][lr] = a0.w;
    As[lc+0][lr+32] = a1.x; As[lc+1][lr+32] = a1.y; As[lc+2][lr+32] = a1.z; As[lc+3][lr+32] = a1.w;
    Bs[lc+0][lr] = b0.x; Bs[lc+1][lr] = b0.y; Bs[lc+2][lr] = b0.z; Bs[lc+3][lr] = b0.w;
    Bs[lc+0][lr+32] = b1.x; Bs[lc+1][lr+32] = b1.y; Bs[lc+2][lr+32] = b1.z; Bs[lc+3][lr+32] = b1.w;
    __syncthreads();
    #pragma unroll
    for (int k = 0; k < 32; ++k) {
      const float4 a4 = *(const float4*)&As[k][ty<<2];
      const float4 b4 = *(const float4*)&Bs[k][tx<<2];
      const float aa[4] = {a4.x, a4.y, a4.z, a4.w};
      const float bb[4] = {b4.x, b4.y, b4.z, b4.w};
      #pragma unroll
      for (int mi = 0; mi < 4; ++mi)
        #pragma unroll
        for (int ni = 0; ni < 4; ++ni)
          acc[mi][ni] += aa[mi]*bb[ni];
    }
  }
  const int h0   = bn*64 + (tx<<2);
  const int part = h0 / DM;
  const int rem  = h0 - part*DM;
  const int n    = rem >> 6;
  const int d0   = rem & 63;
  #pragma unroll
  for (int mi = 0; mi < 4; ++mi) {
    const int r = bm*64 + (ty<<2) + mi;
    const int i = r >> 1, b = r & 1;
    const size_t off = ((size_t)(b*NH + n)*QLEN + i)*DH + d0;
    if (part == 2) {
      *(float4*)&Vo[off] = make_float4(acc[mi][0], acc[mi][1], acc[mi][2], acc[mi][3]);
    } else {
      unsigned short* dst = (part == 0) ? Qo : Ko;
      *(ushort4*)&dst[off] = make_ushort4(f2bf(acc[mi][0]), f2bf(acc[mi][1]),
                                          f2bf(acc[mi][2]), f2bf(acc[mi][3]));
    }
  }
}

// ---------------------------------------------------------------------------
// Kernel 2: V f32 [bn][j][d] -> Vt bf16 [bn][d][j]  (LDS 64x64 transpose)
// ---------------------------------------------------------------------------
__global__ __launch_bounds__(256)
void vt_pack(const float* __restrict__ V, unsigned short* __restrict__ Vt) {
  __shared__ float Ls[64][65];
  const int jt = blockIdx.x, bn = blockIdx.y;
  const int tid = threadIdx.x;
  const size_t base = (size_t)bn * (QLEN*DH);
  {
    const int jl = tid >> 2, dq = (tid & 3) << 4;
    const float* src = &V[base + (size_t)(jt*64 + jl)*DH + dq];
    #pragma unroll
    for (int q = 0; q < 4; ++q) {
      const float4 v = *(const float4*)&src[q*4];
      Ls[jl][dq + q*4 + 0] = v.x; Ls[jl][dq + q*4 + 1] = v.y;
      Ls[jl][dq + q*4 + 2] = v.z; Ls[jl][dq + q*4 + 3] = v.w;
    }
  }
  __syncthreads();
  const int dl = tid >> 2, jq = (tid & 3) << 4;
  unsigned short tb[16];
  #pragma unroll
  for (int e = 0; e < 16; ++e) tb[e] = f2bf(Ls[jq + e][dl]);
  #pragma unroll
  for (int q = 0; q < 4; ++q)
    *(ushort4*)&Vt[base + (size_t)dl*QLEN + jt*64 + jq + q*4] =
        make_ushort4(tb[q*4], tb[q*4+1], tb[q*4+2], tb[q*4+3]);
}

// ---------------------------------------------------------------------------
// Kernel 3: pack r_emb [g][n][d] -> RELp bf16 [n][g][d] (zero pad g>=2048)
//           and rbias [g][n] -> rbp f32 [n][g] (zero pad)
// ---------------------------------------------------------------------------
__global__ __launch_bounds__(256)
void rel_pack(const float* __restrict__ remb, const float* __restrict__ rbias,
              unsigned short* __restrict__ RELp, float* __restrict__ rbp) {
  const int n = blockIdx.y;
  const int g = blockIdx.x*4 + (threadIdx.x >> 6);
  const int d = threadIdx.x & 63;
  const bool ok = g < QLEN;
  const float v = ok ? remb[((size_t)g*NH + n)*DH + d] : 0.f;
  RELp[((size_t)n*RELROWS + g)*DH + d] = f2bf(v);
  if (d == 0) rbp[n*RELROWS + g] = ok ? rbias[g*NH + n] : 0.f;
}

// ---------------------------------------------------------------------------
// Kernel 4: KB[b,n,j] = dot(r_w_bias[n], K[b,n,j,:])  (bf16 K)
// ---------------------------------------------------------------------------
__global__ __launch_bounds__(256)
void kbias_kernel(const unsigned short* __restrict__ K, const float* __restrict__ rwb,
                  float* __restrict__ KB) {
  const int wv = threadIdx.x >> 6, lane = threadIdx.x & 63;
  const int row = blockIdx.x*4 + wv;             // (b*NH+n)*QLEN + j
  const int n = (row >> 11) % NH;
  float v = bf2f(K[(size_t)row*DH + lane]) * rwb[n*DH + lane];
  #pragma unroll
  for (int o = 32; o > 0; o >>= 1) v += __shfl_xor(v, o, 64);
  if (lane == 0) KB[row] = v;
}

// ---------------------------------------------------------------------------
// Kernel 5: MFMA flash attention with rel-shift.
// grid = (32 q-tiles [reversed for load balance], 24 bn), block = 256 (4 waves).
// Wave w owns q-rows it*64 + w*16 .. +15.  No barriers in k-loop: all LDS
// (T strip, P tile) is wave-private.  K/REL/Vt fragments load from global
// (L1/L2-resident; B-fragments are 16B-contiguous rows by construction).
//
// MFMA 16x16x32 layouts (guide §3): A row=lane&15, k=(lane>>4)*8+j;
// B col=lane&15, k=(lane>>4)*8+j; C/D col=lane&15, row=(lane>>4)*4+reg.
// Rel-shift: BD[il][jl] = T[il][63+jl-il_tile], T = Q·REL^T; wave strip
// covers tile-diag cols tbase..tbase+79, tbase = 48-16*wv.
// ---------------------------------------------------------------------------
__global__ __launch_bounds__(256, 3)
void attn_kernel(const unsigned short* __restrict__ Qb,
                 const unsigned short* __restrict__ Kb,
                 const unsigned short* __restrict__ Vt,
                 const unsigned short* __restrict__ RELp,
                 const float* __restrict__ rbp,
                 const float* __restrict__ KB,
                 float* __restrict__ AV) {
  __shared__ float          Tlds[4][16][PADT];
  __shared__ unsigned short Plds[4][16][PADP];
  const int it  = NKT - 1 - blockIdx.x;   // heavy tiles dispatch first
  const int bn  = blockIdx.y;
  const int n   = bn % NH;
  const int tid = threadIdx.x;
  const int wv = tid >> 6, lane = tid & 63;
  const int lrow = lane >> 4;     // 0..3
  const int lcol = lane & 15;
  const int tbase = 48 - 16*wv;
  const size_t base = (size_t)bn * (QLEN*DH);

  float*          Tw = &Tlds[wv][0][0];
  unsigned short* Pw = &Plds[wv][0][0];

  // Q A-fragments (held for whole k-loop)
  const int qi = it*64 + wv*16 + lcol;
  const short8 qf0 = *(const short8*)&Qb[base + (size_t)qi*DH + lrow*8];
  const short8 qf1 = *(const short8*)&Qb[base + (size_t)qi*DH + 32 + lrow*8];

  f32x4 accO[4];
  float m[4], lsum[4];
  #pragma unroll
  for (int r = 0; r < 4; ++r) {
    accO[r] = (f32x4){0.f, 0.f, 0.f, 0.f};
    m[r] = -3.0e38f; lsum[r] = 0.f;
  }

  for (int jt = 0; jt <= it; ++jt) {
    const int r0g = 1984 - 64*(it - jt);
    // ---- T strip = Q * REL^T (5 col-blocks of 16) -> wave-private LDS ----
    #pragma unroll
    for (int cb = 0; cb < 5; ++cb) {
      const int g = r0g + tbase + cb*16 + lcol;      // in [0, 2176)
      const size_t ro = ((size_t)n*RELROWS + g)*DH + lrow*8;
      const short8 r0 = *(const short8*)&RELp[ro];
      const short8 r1 = *(const short8*)&RELp[ro + 32];
      f32x4 tacc = (f32x4){0.f, 0.f, 0.f, 0.f};
      tacc = __builtin_amdgcn_mfma_f32_16x16x32_bf16(qf0, r0, tacc, 0, 0, 0);
      tacc = __builtin_amdgcn_mfma_f32_16x16x32_bf16(qf1, r1, tacc, 0, 0, 0);
      #pragma unroll
      for (int reg = 0; reg < 4; ++reg)
        Tw[(lrow*4 + reg)*PADT + cb*16 + lcol] = tacc[reg];
    }
    // ---- S = Q * K^T ----
    f32x4 s[4];
    #pragma unroll
    for (int cb = 0; cb < 4; ++cb) {
      const size_t ko = base + (size_t)(jt*64 + cb*16 + lcol)*DH + lrow*8;
      const short8 k0 = *(const short8*)&Kb[ko];
      const short8 k1 = *(const short8*)&Kb[ko + 32];
      f32x4 a = (f32x4){0.f, 0.f, 0.f, 0.f};
      a = __builtin_amdgcn_mfma_f32_16x16x32_bf16(qf0, k0, a, 0, 0, 0);
      a = __builtin_amdgcn_mfma_f32_16x16x32_bf16(qf1, k1, a, 0, 0, 0);
      s[cb] = a;
    }
    // ---- combine: + T(diag) + kb[j] + rbias(diag), scale, causal mask ----
    #pragma unroll
    for (int cb = 0; cb < 4; ++cb) {
      const int jg = jt*64 + cb*16 + lcol;
      const float kbv = KB[bn*QLEN + jg];
      #pragma unroll
      for (int reg = 0; reg < 4; ++reg) {
        const int row = lrow*4 + reg;
        const int ig  = it*64 + wv*16 + row;
        const int tc2 = 15 + cb*16 + lcol - row;     // in [0, 79)
        const int gd  = r0g + tbase + tc2;           // = 2047 + jg - ig
        float sv = (s[cb][reg] + Tw[row*PADT + tc2] + kbv + rbp[n*RELROWS + gd]) * SCALE;
        s[cb][reg] = (jg > ig) ? -3.0e38f : sv;
      }
    }
    // ---- online softmax (row lives in a 16-lane group) ----
    #pragma unroll
    for (int reg = 0; reg < 4; ++reg) {
      float mx = fmaxf(fmaxf(s[0][reg], s[1][reg]), fmaxf(s[2][reg], s[3][reg]));
      mx = fmaxf(mx, __shfl_xor(mx, 1, 64));
      mx = fmaxf(mx, __shfl_xor(mx, 2, 64));
      mx = fmaxf(mx, __shfl_xor(mx, 4, 64));
      mx = fmaxf(mx, __shfl_xor(mx, 8, 64));
      const float mn = fmaxf(m[reg], mx);
      const float al = __expf(m[reg] - mn);
      m[reg] = mn;
      float ps = 0.f;
      #pragma unroll
      for (int cb = 0; cb < 4; ++cb) {
        const float p = __expf(s[cb][reg] - mn);
        s[cb][reg] = p; ps += p;
      }
      ps += __shfl_xor(ps, 1, 64);
      ps += __shfl_xor(ps, 2, 64);
      ps += __shfl_xor(ps, 4, 64);
      ps += __shfl_xor(ps, 8, 64);
      lsum[reg] = lsum[reg]*al + ps;
      #pragma unroll
      for (int cb = 0; cb < 4; ++cb) accO[cb][reg] *= al;
      const int row = lrow*4 + reg;
      #pragma unroll
      for (int cb = 0; cb < 4; ++cb)
        Pw[row*PADP + cb*16 + lcol] = f2bf(s[cb][reg]);
    }
    // ---- O += P * V  (A from wave-private LDS, B from Vt rows) ----
    const short8 pa0 = *(const short8*)&Pw[lcol*PADP + lrow*8];
    const short8 pa1 = *(const short8*)&Pw[lcol*PADP + 32 + lrow*8];
    #pragma unroll
    for (int cb = 0; cb < 4; ++cb) {
      const size_t vo = base + (size_t)(cb*16 + lcol)*QLEN + jt*64 + lrow*8;
      const short8 v0 = *(const short8*)&Vt[vo];
      const short8 v1 = *(const short8*)&Vt[vo + 32];
      accO[cb] = __builtin_amdgcn_mfma_f32_16x16x32_bf16(pa0, v0, accO[cb], 0, 0, 0);
      accO[cb] = __builtin_amdgcn_mfma_f32_16x16x32_bf16(pa1, v1, accO[cb], 0, 0, 0);
    }
  }
  #pragma unroll
  for (int reg = 0; reg < 4; ++reg) {
    const float inv = 1.0f / lsum[reg];
    const int i = it*64 + wv*16 + lrow*4 + reg;
    #pragma unroll
    for (int cb = 0; cb < 4; ++cb)
      AV[base + (size_t)i*DH + cb*16 + lcol] = accO[cb][reg] * inv;
  }
}

// ---------------------------------------------------------------------------
// Kernel 6: O-projection GEMM (unchanged).
// ---------------------------------------------------------------------------
__global__ __launch_bounds__(256)
void oproj_gemm(const float* __restrict__ AVp, const float* __restrict__ B,
                float* __restrict__ AO) {
  __shared__ __align__(16) float As[32][68];
  __shared__ __align__(16) float Bs[32][68];
  const int bn = blockIdx.x;      // 12
  const int bm = blockIdx.y;      // 64
  const int tx = threadIdx.x, ty = threadIdx.y;
  const int t  = ty*16 + tx;
  const int lr = t >> 3;
  const int lc = (t & 7) << 2;
  float acc[4][4] = {};
  for (int kk = 0; kk < DM; kk += 32) {
    const int h = kk + lc, hn = h >> 6, hd = h & 63;
    const int r0r = bm*64 + lr, r1r = r0r + 32;
    const int i0 = r0r >> 1, b0v = r0r & 1;
    const int i1 = r1r >> 1, b1v = r1r & 1;
    const float4 a0 = *(const float4*)&AVp[((size_t)(b0v*NH + hn)*QLEN + i0)*DH + hd];
    const float4 a1 = *(const float4*)&AVp[((size_t)(b1v*NH + hn)*QLEN + i1)*DH + hd];
    const float4 b0 = *(const float4*)&B[(size_t)(bn*64 + lr     )*DM + kk + lc];
    const float4 b1 = *(const float4*)&B[(size_t)(bn*64 + lr + 32)*DM + kk + lc];
    __syncthreads();
    As[lc+0][lr] = a0.x; As[lc+1][lr] = a0.y; As[lc+2][lr] = a0.z; As[lc+3][lr] = a0.w;
    As[lc+0][lr+32] = a1.x; As[lc+1][lr+32] = a1.y; As[lc+2][lr+32] = a1.z; As[lc+3][lr+32] = a1.w;
    Bs[lc+0][lr] = b0.x; Bs[lc+1][lr] = b0.y; Bs[lc+2][lr] = b0.z; Bs[lc+3][lr] = b0.w;
    Bs[lc+0][lr+32] = b1.x; Bs[lc+1][lr+32] = b1.y; Bs[lc+2][lr+32] = b1.z; Bs[lc+3][lr+32] = b1.w;
    __syncthreads();
    #pragma unroll
    for (int k = 0; k < 32; ++k) {
      const float4 a4 = *(const float4*)&As[k][ty<<2];
      const float4 b4 = *(const float4*)&Bs[k][tx<<2];
      const float aa[4] = {a4.x, a4.y, a4.z, a4.w};
      const float bb[4] = {b4.x, b4.y, b4.z, b4.w};
      #pragma unroll
      for (int mi = 0; mi < 4; ++mi)
        #pragma unroll
        for (int ni = 0; ni < 4; ++ni)
          acc[mi][ni] += aa[mi]*bb[ni];
    }
  }
  #pragma unroll
  for (int mi = 0; mi < 4; ++mi) {
    const int r = bm*64 + (ty<<2) + mi;
    const float4 v = make_float4(acc[mi][0], acc[mi][1], acc[mi][2], acc[mi][3]);
    *(float4*)&AO[(size_t)r*DM + bn*64 + (tx<<2)] = v;
  }
}

// ---------------------------------------------------------------------------
// Kernel 7: residual + LayerNorm (unchanged).
// ---------------------------------------------------------------------------
__global__ __launch_bounds__(256)
void ln_kernel(const float* __restrict__ AO, const float* __restrict__ W,
               const float* __restrict__ gamma, const float* __restrict__ beta,
               float* __restrict__ out) {
  const int r = blockIdx.x;
  const int tid = threadIdx.x;
  const int wv = tid >> 6, lane = tid & 63;
  float x[3];
  #pragma unroll
  for (int q = 0; q < 3; ++q) {
    const int mcol = tid + q*256;
    x[q] = AO[(size_t)r*DM + mcol] + W[(size_t)r*DM + mcol];
  }
  float s1 = x[0] + x[1] + x[2];
  float s2 = x[0]*x[0] + x[1]*x[1] + x[2]*x[2];
  #pragma unroll
  for (int o = 32; o > 0; o >>= 1) { s1 += __shfl_xor(s1, o, 64); s2 += __shfl_xor(s2, o, 64); }
  __shared__ float a1[4], a2[4];
  if (lane == 0) { a1[wv] = s1; a2[wv] = s2; }
  __syncthreads();
  s1 = a1[0] + a1[1] + a1[2] + a1[3];
  s2 = a2[0] + a2[1] + a2[2] + a2[3];
  const float mu  = s1 * (1.0f/DM);
  const float var = s2 * (1.0f/DM) - mu*mu;
  const float rs  = rsqrtf(var + 1e-5f);
  #pragma unroll
  for (int q = 0; q < 3; ++q) {
    const int mcol = tid + q*256;
    out[(size_t)r*DM + mcol] = (x[q] - mu)*rs*gamma[mcol] + beta[mcol];
  }
}

// ---------------------------------------------------------------------------
extern "C" void kernel_launch(void* const* d_in, const int* in_sizes, int n_in,
                              void* d_out, int out_size, void* d_ws, size_t ws_size,
                              hipStream_t stream) {
  const float* w      = (const float*)d_in[0];
  const float* r_emb  = (const float*)d_in[1];
  const float* r_wb   = (const float*)d_in[2];
  const float* r_bias = (const float*)d_in[3];
  const float* qkv_w  = (const float*)d_in[4];
  const float* o_w    = (const float*)d_in[5];
  const float* ln_g   = (const float*)d_in[6];
  const float* ln_b   = (const float*)d_in[7];
  float* out = (float*)d_out;
  float* ws  = (float*)d_ws;

  const size_t QS = (size_t)BSZ*NH*QLEN*DH;     // 3,145,728
  float* Vb  = ws;                              // f32 V (pre-transpose)
  float* AVb = ws + QS;                         // f32 attention output
  unsigned short* Qb   = (unsigned short*)(ws + 2*QS);
  unsigned short* Kbp  = Qb + QS;
  unsigned short* Vtp  = Kbp + QS;
  unsigned short* RELp = Vtp + QS;              // NH*RELROWS*DH
  float* rbp = (float*)(RELp + (size_t)NH*RELROWS*DH);
  float* KBb = rbp + NH*RELROWS;
  float* AOb = Vb;                              // reuse V slot after vt_pack

  qkv_gemm<<<dim3(HID/64, (QLEN*BSZ)/64), dim3(16,16), 0, stream>>>(w, qkv_w, Qb, Kbp, Vb);
  vt_pack<<<dim3(NKT, BSZ*NH), dim3(256), 0, stream>>>(Vb, Vtp);
  rel_pack<<<dim3(RELROWS/4, NH), dim3(256), 0, stream>>>(r_emb, r_bias, RELp, rbp);
  kbias_kernel<<<dim3(BSZ*NH*QLEN/4), dim3(256), 0, stream>>>(Kbp, r_wb, KBb);
  attn_kernel<<<dim3(NKT, BSZ*NH), dim3(256), 0, stream>>>(Qb, Kbp, Vtp, RELp, rbp, KBb, AVb);
  oproj_gemm<<<dim3(DM/64, (QLEN*BSZ)/64), dim3(16,16), 0, stream>>>(AVb, o_w, AOb);
  ln_kernel<<<dim3(QLEN*BSZ), dim3(256), 0, stream>>>(AOb, w, ln_g, ln_b, out);
}

// Round 3
// 410.375 us; speedup vs baseline: 9.2840x; 1.4179x over previous
//
#include <hip/hip_runtime.h>

#define QLEN 2048
#define BSZ  2
#define NH   12
#define DH   64
#define DM   768
#define HID  2304
#define SCALE 0.125f
#define RELROWS 2176     // 2048 + 128 zero pad
#define PADT 84          // T strip row stride (f32)
#define PADP 72          // P tile row stride (bf16)

typedef __attribute__((ext_vector_type(8))) short short8;
typedef __attribute__((ext_vector_type(4))) float f32x4;
typedef unsigned short ushort_t;

static __device__ __forceinline__ ushort_t f2bf(float x) {
  unsigned u = __float_as_uint(x);
  return (ushort_t)((u + 0x7FFFu + ((u >> 16) & 1u)) >> 16);
}
static __device__ __forceinline__ float bf2f(ushort_t h) {
  return __uint_as_float(((unsigned)h) << 16);
}

// ---------------------------------------------------------------------------
// Kernel 0: f32 -> bf16 pack (8 elements/thread)
// ---------------------------------------------------------------------------
__global__ __launch_bounds__(256)
void pack_bf16(const float* __restrict__ src, ushort_t* __restrict__ dst, int n8) {
  const int idx = blockIdx.x*256 + threadIdx.x;
  if (idx >= n8) return;
  const float4 a = *(const float4*)&src[(size_t)idx*8];
  const float4 b = *(const float4*)&src[(size_t)idx*8 + 4];
  short8 o;
  o[0]=(short)f2bf(a.x); o[1]=(short)f2bf(a.y); o[2]=(short)f2bf(a.z); o[3]=(short)f2bf(a.w);
  o[4]=(short)f2bf(b.x); o[5]=(short)f2bf(b.y); o[6]=(short)f2bf(b.z); o[7]=(short)f2bf(b.w);
  *(short8*)&dst[(size_t)idx*8] = o;
}

// ---------------------------------------------------------------------------
// Kernel 1: QKV projection, bf16 MFMA.  C[r][h] = sum_m A[r][m]*B[h][m]
// A = w bf16 [4096][768], B = qkv_w bf16 [2304][768] (B^T form).
// 128x128 tile, 4 waves (2x2), wave tile 64x64 (4x4 frags 16x16), BK=64.
// LDS XOR-swizzled (byte ^= (row&7)<<4) on both write and read.
// Epilogue scatters bf16 into Q/K/V [b][n][i][d].
// ---------------------------------------------------------------------------
__global__ __launch_bounds__(256)
void qkv_mfma(const ushort_t* __restrict__ A, const ushort_t* __restrict__ B,
              ushort_t* __restrict__ Qo, ushort_t* __restrict__ Ko,
              ushort_t* __restrict__ Vo) {
  __shared__ __align__(16) ushort_t As[128*64];
  __shared__ __align__(16) ushort_t Bs[128*64];
  const int bx = blockIdx.x;        // 18 N-tiles
  const int by = blockIdx.y;        // 32 M-tiles
  const int rbase = by*128, cbase = bx*128;
  const int tid = threadIdx.x;
  const int wv = tid>>6, lane = tid&63, lrow = lane>>4, lcol = lane&15;
  const int wr = wv>>1, wc = wv&1;
  const int sr = tid>>3, sc = tid&7;

  f32x4 acc[4][4];
  #pragma unroll
  for (int m = 0; m < 4; ++m)
    #pragma unroll
    for (int nn = 0; nn < 4; ++nn)
      acc[m][nn] = (f32x4){0.f,0.f,0.f,0.f};

  for (int kk = 0; kk < DM; kk += 64) {
    __syncthreads();
    #pragma unroll
    for (int q = 0; q < 4; ++q) {
      const int row = sr + 32*q;
      const short8 va = *(const short8*)&A[(size_t)(rbase+row)*DM + kk + sc*8];
      *(short8*)((char*)As + row*128 + ((sc*16) ^ ((row&7)<<4))) = va;
      const short8 vb = *(const short8*)&B[(size_t)(cbase+row)*DM + kk + sc*8];
      *(short8*)((char*)Bs + row*128 + ((sc*16) ^ ((row&7)<<4))) = vb;
    }
    __syncthreads();
    short8 af[4][2], bfr[4][2];
    #pragma unroll
    for (int m = 0; m < 4; ++m) {
      const int row = wr*64 + m*16 + lcol;
      af[m][0] = *(const short8*)((const char*)As + row*128 + (((     lrow*16)) ^ ((row&7)<<4)));
      af[m][1] = *(const short8*)((const char*)As + row*128 + (((64 + lrow*16)) ^ ((row&7)<<4)));
    }
    #pragma unroll
    for (int nn = 0; nn < 4; ++nn) {
      const int row = wc*64 + nn*16 + lcol;
      bfr[nn][0] = *(const short8*)((const char*)Bs + row*128 + (((     lrow*16)) ^ ((row&7)<<4)));
      bfr[nn][1] = *(const short8*)((const char*)Bs + row*128 + (((64 + lrow*16)) ^ ((row&7)<<4)));
    }
    #pragma unroll
    for (int m = 0; m < 4; ++m)
      #pragma unroll
      for (int nn = 0; nn < 4; ++nn) {
        acc[m][nn] = __builtin_amdgcn_mfma_f32_16x16x32_bf16(af[m][0], bfr[nn][0], acc[m][nn], 0, 0, 0);
        acc[m][nn] = __builtin_amdgcn_mfma_f32_16x16x32_bf16(af[m][1], bfr[nn][1], acc[m][nn], 0, 0, 0);
      }
  }
  const int part = cbase / DM;      // 128 | 768 boundaries: uniform per block
  ushort_t* dst = (part == 0) ? Qo : ((part == 1) ? Ko : Vo);
  #pragma unroll
  for (int nn = 0; nn < 4; ++nn) {
    const int h  = cbase - part*DM + wc*64 + nn*16;
    const int nh = h >> 6;
    const int d  = (h & 63) + lcol;
    #pragma unroll
    for (int m = 0; m < 4; ++m)
      #pragma unroll
      for (int reg = 0; reg < 4; ++reg) {
        const int r = rbase + wr*64 + m*16 + lrow*4 + reg;
        const int i = r >> 1, b = r & 1;
        dst[((size_t)(b*NH + nh)*QLEN + i)*DH + d] = f2bf(acc[m][nn][reg]);
      }
  }
}

// ---------------------------------------------------------------------------
// Kernel 2: V bf16 [bn][j][d] -> Vt bf16 [bn][d][j]  (LDS transpose)
// ---------------------------------------------------------------------------
__global__ __launch_bounds__(256)
void vt_pack(const ushort_t* __restrict__ V, ushort_t* __restrict__ Vt) {
  __shared__ ushort_t Ls[64][72];
  const int jt = blockIdx.x, bn = blockIdx.y;
  const int tid = threadIdx.x;
  const size_t base = (size_t)bn * (QLEN*DH);
  #pragma unroll
  for (int q = 0; q < 2; ++q) {
    const int row = (tid>>3) + 32*q;
    const int c8  = (tid&7)*8;
    *(short8*)&Ls[row][c8] = *(const short8*)&V[base + (size_t)(jt*64+row)*DH + c8];
  }
  __syncthreads();
  #pragma unroll
  for (int q = 0; q < 2; ++q) {
    const int d  = (tid>>3) + 32*q;
    const int j8 = (tid&7)*8;
    short8 o;
    #pragma unroll
    for (int e = 0; e < 8; ++e) o[e] = (short)Ls[j8+e][d];
    *(short8*)&Vt[base + (size_t)d*QLEN + jt*64 + j8] = o;
  }
}

// ---------------------------------------------------------------------------
// Kernel 3: pack r_emb [g][n][d] -> RELp bf16 [n][g][d] (zero pad g>=2048)
//           and rbias [g][n] -> rbp f32 [n][g] (zero pad)
// ---------------------------------------------------------------------------
__global__ __launch_bounds__(256)
void rel_pack(const float* __restrict__ remb, const float* __restrict__ rbias,
              ushort_t* __restrict__ RELp, float* __restrict__ rbp) {
  const int n = blockIdx.y;
  const int g = blockIdx.x*4 + (threadIdx.x >> 6);
  const int d = threadIdx.x & 63;
  const bool ok = g < QLEN;
  const float v = ok ? remb[((size_t)g*NH + n)*DH + d] : 0.f;
  RELp[((size_t)n*RELROWS + g)*DH + d] = f2bf(v);
  if (d == 0) rbp[n*RELROWS + g] = ok ? rbias[g*NH + n] : 0.f;
}

// ---------------------------------------------------------------------------
// Kernel 4: KB[b,n,j] = dot(r_w_bias[n], K[b,n,j,:])  (bf16 K)
// ---------------------------------------------------------------------------
__global__ __launch_bounds__(256)
void kbias_kernel(const ushort_t* __restrict__ K, const float* __restrict__ rwb,
                  float* __restrict__ KB) {
  const int wv = threadIdx.x >> 6, lane = threadIdx.x & 63;
  const int row = blockIdx.x*4 + wv;             // (b*NH+n)*QLEN + j
  const int n = (row >> 11) % NH;
  float v = bf2f(K[(size_t)row*DH + lane]) * rwb[n*DH + lane];
  #pragma unroll
  for (int o = 32; o > 0; o >>= 1) v += __shfl_xor(v, o, 64);
  if (lane == 0) KB[row] = v;
}

// ---------------------------------------------------------------------------
// Kernel 5: MFMA flash attention with rel-shift.
// grid = (64 q-tiles of 32 rows [reversed], 24 bn), block = 128 (2 waves).
// Wave w owns q-rows it32*32 + w*16 .. +15.  No barriers in k-loop (LDS is
// wave-private).  rbias folded into the T-strip LDS write (row-independent).
// ---------------------------------------------------------------------------
__global__ __launch_bounds__(128)
void attn_kernel(const ushort_t* __restrict__ Qb,
                 const ushort_t* __restrict__ Kb,
                 const ushort_t* __restrict__ Vt,
                 const ushort_t* __restrict__ RELp,
                 const float* __restrict__ rbp,
                 const float* __restrict__ KB,
                 ushort_t* __restrict__ AV) {
  __shared__ float    Tlds[2][16][PADT];
  __shared__ ushort_t Plds[2][16][PADP];
  const int it32 = 63 - blockIdx.x;       // heavy tiles dispatch first
  const int bn   = blockIdx.y;
  const int n    = bn % NH;
  const int tid  = threadIdx.x;
  const int wv = tid >> 6, lane = tid & 63;
  const int lrow = lane >> 4;             // 0..3
  const int lcol = lane & 15;
  const size_t base = (size_t)bn * (QLEN*DH);

  float*    Tw = &Tlds[wv][0][0];
  ushort_t* Pw = &Plds[wv][0][0];

  const int qi = it32*32 + wv*16 + lcol;
  const short8 qf0 = *(const short8*)&Qb[base + (size_t)qi*DH + lrow*8];
  const short8 qf1 = *(const short8*)&Qb[base + (size_t)qi*DH + 32 + lrow*8];

  f32x4 accO[4];
  float m[4], lsum[4];
  #pragma unroll
  for (int r = 0; r < 4; ++r) {
    accO[r] = (f32x4){0.f, 0.f, 0.f, 0.f};
    m[r] = -3.0e38f; lsum[r] = 0.f;
  }

  const int jt_max = it32 >> 1;
  for (int jt = 0; jt <= jt_max; ++jt) {
    const int gbase = 2032 + jt*64 - it32*32 - wv*16;   // in [0, 2032]
    // ---- T strip = Q * REL^T (+ rbias), 5 col-blocks -> wave-private LDS ----
    #pragma unroll
    for (int cb = 0; cb < 5; ++cb) {
      const int g = gbase + cb*16 + lcol;               // < 2176
      const size_t ro = ((size_t)n*RELROWS + g)*DH + lrow*8;
      const short8 r0 = *(const short8*)&RELp[ro];
      const short8 r1 = *(const short8*)&RELp[ro + 32];
      f32x4 tacc = (f32x4){0.f, 0.f, 0.f, 0.f};
      tacc = __builtin_amdgcn_mfma_f32_16x16x32_bf16(qf0, r0, tacc, 0, 0, 0);
      tacc = __builtin_amdgcn_mfma_f32_16x16x32_bf16(qf1, r1, tacc, 0, 0, 0);
      const float rb = rbp[n*RELROWS + g];              // row-independent
      #pragma unroll
      for (int reg = 0; reg < 4; ++reg)
        Tw[(lrow*4 + reg)*PADT + cb*16 + lcol] = tacc[reg] + rb;
    }
    // ---- S = Q * K^T ----
    f32x4 s[4];
    #pragma unroll
    for (int cb = 0; cb < 4; ++cb) {
      const size_t ko = base + (size_t)(jt*64 + cb*16 + lcol)*DH + lrow*8;
      const short8 k0 = *(const short8*)&Kb[ko];
      const short8 k1 = *(const short8*)&Kb[ko + 32];
      f32x4 a = (f32x4){0.f, 0.f, 0.f, 0.f};
      a = __builtin_amdgcn_mfma_f32_16x16x32_bf16(qf0, k0, a, 0, 0, 0);
      a = __builtin_amdgcn_mfma_f32_16x16x32_bf16(qf1, k1, a, 0, 0, 0);
      s[cb] = a;
    }
    // ---- combine: + T(diag, incl rbias) + kb[j], scale, causal mask ----
    #pragma unroll
    for (int cb = 0; cb < 4; ++cb) {
      const int jg = jt*64 + cb*16 + lcol;
      const float kbv = KB[bn*QLEN + jg];
      #pragma unroll
      for (int reg = 0; reg < 4; ++reg) {
        const int row = lrow*4 + reg;
        const int ig  = it32*32 + wv*16 + row;
        const int tc2 = 15 + cb*16 + lcol - row;        // [0, 79)
        float sv = (s[cb][reg] + Tw[row*PADT + tc2] + kbv) * SCALE;
        s[cb][reg] = (jg > ig) ? -3.0e38f : sv;
      }
    }
    // ---- online softmax (row lives in a 16-lane group) ----
    #pragma unroll
    for (int reg = 0; reg < 4; ++reg) {
      float mx = fmaxf(fmaxf(s[0][reg], s[1][reg]), fmaxf(s[2][reg], s[3][reg]));
      mx = fmaxf(mx, __shfl_xor(mx, 1, 64));
      mx = fmaxf(mx, __shfl_xor(mx, 2, 64));
      mx = fmaxf(mx, __shfl_xor(mx, 4, 64));
      mx = fmaxf(mx, __shfl_xor(mx, 8, 64));
      const float mn = fmaxf(m[reg], mx);
      const float al = __expf(m[reg] - mn);
      m[reg] = mn;
      float ps = 0.f;
      #pragma unroll
      for (int cb = 0; cb < 4; ++cb) {
        const float p = __expf(s[cb][reg] - mn);
        s[cb][reg] = p; ps += p;
      }
      ps += __shfl_xor(ps, 1, 64);
      ps += __shfl_xor(ps, 2, 64);
      ps += __shfl_xor(ps, 4, 64);
      ps += __shfl_xor(ps, 8, 64);
      lsum[reg] = lsum[reg]*al + ps;
      #pragma unroll
      for (int cb = 0; cb < 4; ++cb) accO[cb][reg] *= al;
      const int row = lrow*4 + reg;
      #pragma unroll
      for (int cb = 0; cb < 4; ++cb)
        Pw[row*PADP + cb*16 + lcol] = f2bf(s[cb][reg]);
    }
    // ---- O += P * V ----
    const short8 pa0 = *(const short8*)&Pw[lcol*PADP + lrow*8];
    const short8 pa1 = *(const short8*)&Pw[lcol*PADP + 32 + lrow*8];
    #pragma unroll
    for (int cb = 0; cb < 4; ++cb) {
      const size_t vo = base + (size_t)(cb*16 + lcol)*QLEN + jt*64 + lrow*8;
      const short8 v0 = *(const short8*)&Vt[vo];
      const short8 v1 = *(const short8*)&Vt[vo + 32];
      accO[cb] = __builtin_amdgcn_mfma_f32_16x16x32_bf16(pa0, v0, accO[cb], 0, 0, 0);
      accO[cb] = __builtin_amdgcn_mfma_f32_16x16x32_bf16(pa1, v1, accO[cb], 0, 0, 0);
    }
  }
  #pragma unroll
  for (int reg = 0; reg < 4; ++reg) {
    const float inv = 1.0f / lsum[reg];
    const int i = it32*32 + wv*16 + lrow*4 + reg;
    #pragma unroll
    for (int cb = 0; cb < 4; ++cb)
      AV[base + (size_t)i*DH + cb*16 + lcol] = f2bf(accO[cb][reg] * inv);
  }
}

// ---------------------------------------------------------------------------
// Kernel 6: O-projection, bf16 MFMA.  AO[r][m] = sum_h AV[r][h]*o_w[m][h]
// A gathered from AV bf16 [b][n][i][d] (K-step 64 == one head), f32 output.
// ---------------------------------------------------------------------------
__global__ __launch_bounds__(256)
void oproj_mfma(const ushort_t* __restrict__ AVp, const ushort_t* __restrict__ B,
                float* __restrict__ AO) {
  __shared__ __align__(16) ushort_t As[128*64];
  __shared__ __align__(16) ushort_t Bs[128*64];
  const int bx = blockIdx.x;        // 6 N-tiles
  const int by = blockIdx.y;        // 32 M-tiles
  const int rbase = by*128, cbase = bx*128;
  const int tid = threadIdx.x;
  const int wv = tid>>6, lane = tid&63, lrow = lane>>4, lcol = lane&15;
  const int wr = wv>>1, wc = wv&1;
  const int sr = tid>>3, sc = tid&7;

  f32x4 acc[4][4];
  #pragma unroll
  for (int m = 0; m < 4; ++m)
    #pragma unroll
    for (int nn = 0; nn < 4; ++nn)
      acc[m][nn] = (f32x4){0.f,0.f,0.f,0.f};

  for (int kk = 0; kk < DM; kk += 64) {
    const int nh = kk >> 6;         // head index
    __syncthreads();
    #pragma unroll
    for (int q = 0; q < 4; ++q) {
      const int row = sr + 32*q;
      const int r = rbase + row, i = r >> 1, b = r & 1;
      const short8 va = *(const short8*)&AVp[((size_t)(b*NH + nh)*QLEN + i)*DH + sc*8];
      *(short8*)((char*)As + row*128 + ((sc*16) ^ ((row&7)<<4))) = va;
      const short8 vb = *(const short8*)&B[(size_t)(cbase+row)*DM + kk + sc*8];
      *(short8*)((char*)Bs + row*128 + ((sc*16) ^ ((row&7)<<4))) = vb;
    }
    __syncthreads();
    short8 af[4][2], bfr[4][2];
    #pragma unroll
    for (int m = 0; m < 4; ++m) {
      const int row = wr*64 + m*16 + lcol;
      af[m][0] = *(const short8*)((const char*)As + row*128 + (((     lrow*16)) ^ ((row&7)<<4)));
      af[m][1] = *(const short8*)((const char*)As + row*128 + (((64 + lrow*16)) ^ ((row&7)<<4)));
    }
    #pragma unroll
    for (int nn = 0; nn < 4; ++nn) {
      const int row = wc*64 + nn*16 + lcol;
      bfr[nn][0] = *(const short8*)((const char*)Bs + row*128 + (((     lrow*16)) ^ ((row&7)<<4)));
      bfr[nn][1] = *(const short8*)((const char*)Bs + row*128 + (((64 + lrow*16)) ^ ((row&7)<<4)));
    }
    #pragma unroll
    for (int m = 0; m < 4; ++m)
      #pragma unroll
      for (int nn = 0; nn < 4; ++nn) {
        acc[m][nn] = __builtin_amdgcn_mfma_f32_16x16x32_bf16(af[m][0], bfr[nn][0], acc[m][nn], 0, 0, 0);
        acc[m][nn] = __builtin_amdgcn_mfma_f32_16x16x32_bf16(af[m][1], bfr[nn][1], acc[m][nn], 0, 0, 0);
      }
  }
  #pragma unroll
  for (int nn = 0; nn < 4; ++nn) {
    const int mcol = cbase + wc*64 + nn*16 + lcol;
    #pragma unroll
    for (int mi = 0; mi < 4; ++mi)
      #pragma unroll
      for (int reg = 0; reg < 4; ++reg) {
        const int r = rbase + wr*64 + mi*16 + lrow*4 + reg;
        AO[(size_t)r*DM + mcol] = acc[mi][nn][reg];
      }
  }
}

// ---------------------------------------------------------------------------
// Kernel 7: residual + LayerNorm.
// ---------------------------------------------------------------------------
__global__ __launch_bounds__(256)
void ln_kernel(const float* __restrict__ AO, const float* __restrict__ W,
               const float* __restrict__ gamma, const float* __restrict__ beta,
               float* __restrict__ out) {
  const int r = blockIdx.x;
  const int tid = threadIdx.x;
  const int wv = tid >> 6, lane = tid & 63;
  float x[3];
  #pragma unroll
  for (int q = 0; q < 3; ++q) {
    const int mcol = tid + q*256;
    x[q] = AO[(size_t)r*DM + mcol] + W[(size_t)r*DM + mcol];
  }
  float s1 = x[0] + x[1] + x[2];
  float s2 = x[0]*x[0] + x[1]*x[1] + x[2]*x[2];
  #pragma unroll
  for (int o = 32; o > 0; o >>= 1) { s1 += __shfl_xor(s1, o, 64); s2 += __shfl_xor(s2, o, 64); }
  __shared__ float a1[4], a2[4];
  if (lane == 0) { a1[wv] = s1; a2[wv] = s2; }
  __syncthreads();
  s1 = a1[0] + a1[1] + a1[2] + a1[3];
  s2 = a2[0] + a2[1] + a2[2] + a2[3];
  const float mu  = s1 * (1.0f/DM);
  const float var = s2 * (1.0f/DM) - mu*mu;
  const float rs  = rsqrtf(var + 1e-5f);
  #pragma unroll
  for (int q = 0; q < 3; ++q) {
    const int mcol = tid + q*256;
    out[(size_t)r*DM + mcol] = (x[q] - mu)*rs*gamma[mcol] + beta[mcol];
  }
}

// ---------------------------------------------------------------------------
extern "C" void kernel_launch(void* const* d_in, const int* in_sizes, int n_in,
                              void* d_out, int out_size, void* d_ws, size_t ws_size,
                              hipStream_t stream) {
  const float* w      = (const float*)d_in[0];
  const float* r_emb  = (const float*)d_in[1];
  const float* r_wb   = (const float*)d_in[2];
  const float* r_bias = (const float*)d_in[3];
  const float* qkv_w  = (const float*)d_in[4];
  const float* o_w    = (const float*)d_in[5];
  const float* ln_g   = (const float*)d_in[6];
  const float* ln_b   = (const float*)d_in[7];
  float* out = (float*)d_out;

  const size_t QS = (size_t)BSZ*NH*QLEN*DH;       // 3,145,728 elems
  ushort_t* u      = (ushort_t*)d_ws;
  ushort_t* wbf    = u;                           // QS         (dead after qkv_mfma)
  ushort_t* qkvwbf = wbf + QS;                    // HID*DM     (dead after qkv_mfma)
  ushort_t* Vb16   = qkvwbf + (size_t)HID*DM;     // QS         (dead after vt_pack)
  ushort_t* Qb     = Vb16 + QS;
  ushort_t* Kb     = Qb + QS;
  ushort_t* Vt     = Kb + QS;
  ushort_t* AVb16  = Vt + QS;
  ushort_t* owbf   = AVb16 + QS;                  // DM*DM
  ushort_t* RELp   = owbf + (size_t)DM*DM;        // NH*RELROWS*DH
  float* rbp = (float*)(RELp + (size_t)NH*RELROWS*DH);
  float* KBb = rbp + NH*RELROWS;
  float* AO  = (float*)d_ws;                      // aliases wbf/qkvwbf/Vb16 (dead by oproj)

  pack_bf16<<<dim3(1536), dim3(256), 0, stream>>>(w, wbf, (int)(QS/8));
  pack_bf16<<<dim3(864),  dim3(256), 0, stream>>>(qkv_w, qkvwbf, HID*DM/8);
  pack_bf16<<<dim3(288),  dim3(256), 0, stream>>>(o_w, owbf, DM*DM/8);

  qkv_mfma<<<dim3(HID/128, (QLEN*BSZ)/128), dim3(256), 0, stream>>>(wbf, qkvwbf, Qb, Kb, Vb16);
  vt_pack<<<dim3(QLEN/64, BSZ*NH), dim3(256), 0, stream>>>(Vb16, Vt);
  rel_pack<<<dim3(RELROWS/4, NH), dim3(256), 0, stream>>>(r_emb, r_bias, RELp, rbp);
  kbias_kernel<<<dim3(BSZ*NH*QLEN/4), dim3(256), 0, stream>>>(Kb, r_wb, KBb);
  attn_kernel<<<dim3(64, BSZ*NH), dim3(128), 0, stream>>>(Qb, Kb, Vt, RELp, rbp, KBb, AVb16);
  oproj_mfma<<<dim3(DM/128, (QLEN*BSZ)/128), dim3(256), 0, stream>>>(AVb16, owbf, AO);
  ln_kernel<<<dim3(QLEN*BSZ), dim3(256), 0, stream>>>(AO, w, ln_g, ln_b, out);
}

// Round 4
// 397.844 us; speedup vs baseline: 9.5764x; 1.0315x over previous
//
#include <hip/hip_runtime.h>

#define QLEN 2048
#define BSZ  2
#define NH   12
#define DH   64
#define DM   768
#define HID  2304
#define SCALE 0.125f
#define RELROWS 2176     // 2048 + 128 zero pad
#define PADT2 152        // T strip row stride (bf16 elems)
#define PADP  136        // P tile row stride (bf16 elems)

typedef __attribute__((ext_vector_type(8))) short short8;
typedef __attribute__((ext_vector_type(4))) float f32x4;
typedef unsigned short ushort_t;

static __device__ __forceinline__ ushort_t f2bf(float x) {
  unsigned u = __float_as_uint(x);
  return (ushort_t)((u + 0x7FFFu + ((u >> 16) & 1u)) >> 16);
}
static __device__ __forceinline__ float bf2f(ushort_t h) {
  return __uint_as_float(((unsigned)h) << 16);
}

// ---------------------------------------------------------------------------
// Kernel 0: f32 -> bf16 pack (8 elements/thread)
// ---------------------------------------------------------------------------
__global__ __launch_bounds__(256)
void pack_bf16(const float* __restrict__ src, ushort_t* __restrict__ dst, int n8) {
  const int idx = blockIdx.x*256 + threadIdx.x;
  if (idx >= n8) return;
  const float4 a = *(const float4*)&src[(size_t)idx*8];
  const float4 b = *(const float4*)&src[(size_t)idx*8 + 4];
  short8 o;
  o[0]=(short)f2bf(a.x); o[1]=(short)f2bf(a.y); o[2]=(short)f2bf(a.z); o[3]=(short)f2bf(a.w);
  o[4]=(short)f2bf(b.x); o[5]=(short)f2bf(b.y); o[6]=(short)f2bf(b.z); o[7]=(short)f2bf(b.w);
  *(short8*)&dst[(size_t)idx*8] = o;
}

// ---------------------------------------------------------------------------
// Kernel 1: QKV projection, bf16 MFMA.  Q part pre-scaled by SCALE.
// ---------------------------------------------------------------------------
__global__ __launch_bounds__(256)
void qkv_mfma(const ushort_t* __restrict__ A, const ushort_t* __restrict__ B,
              ushort_t* __restrict__ Qo, ushort_t* __restrict__ Ko,
              ushort_t* __restrict__ Vo) {
  __shared__ __align__(16) ushort_t As[128*64];
  __shared__ __align__(16) ushort_t Bs[128*64];
  const int bx = blockIdx.x;        // 18 N-tiles
  const int by = blockIdx.y;        // 32 M-tiles
  const int rbase = by*128, cbase = bx*128;
  const int tid = threadIdx.x;
  const int wv = tid>>6, lane = tid&63, lrow = lane>>4, lcol = lane&15;
  const int wr = wv>>1, wc = wv&1;
  const int sr = tid>>3, sc = tid&7;

  f32x4 acc[4][4];
  #pragma unroll
  for (int m = 0; m < 4; ++m)
    #pragma unroll
    for (int nn = 0; nn < 4; ++nn)
      acc[m][nn] = (f32x4){0.f,0.f,0.f,0.f};

  for (int kk = 0; kk < DM; kk += 64) {
    __syncthreads();
    #pragma unroll
    for (int q = 0; q < 4; ++q) {
      const int row = sr + 32*q;
      const short8 va = *(const short8*)&A[(size_t)(rbase+row)*DM + kk + sc*8];
      *(short8*)((char*)As + row*128 + ((sc*16) ^ ((row&7)<<4))) = va;
      const short8 vb = *(const short8*)&B[(size_t)(cbase+row)*DM + kk + sc*8];
      *(short8*)((char*)Bs + row*128 + ((sc*16) ^ ((row&7)<<4))) = vb;
    }
    __syncthreads();
    short8 af[4][2], bfr[4][2];
    #pragma unroll
    for (int m = 0; m < 4; ++m) {
      const int row = wr*64 + m*16 + lcol;
      af[m][0] = *(const short8*)((const char*)As + row*128 + (((     lrow*16)) ^ ((row&7)<<4)));
      af[m][1] = *(const short8*)((const char*)As + row*128 + (((64 + lrow*16)) ^ ((row&7)<<4)));
    }
    #pragma unroll
    for (int nn = 0; nn < 4; ++nn) {
      const int row = wc*64 + nn*16 + lcol;
      bfr[nn][0] = *(const short8*)((const char*)Bs + row*128 + (((     lrow*16)) ^ ((row&7)<<4)));
      bfr[nn][1] = *(const short8*)((const char*)Bs + row*128 + (((64 + lrow*16)) ^ ((row&7)<<4)));
    }
    #pragma unroll
    for (int m = 0; m < 4; ++m)
      #pragma unroll
      for (int nn = 0; nn < 4; ++nn) {
        acc[m][nn] = __builtin_amdgcn_mfma_f32_16x16x32_bf16(af[m][0], bfr[nn][0], acc[m][nn], 0, 0, 0);
        acc[m][nn] = __builtin_amdgcn_mfma_f32_16x16x32_bf16(af[m][1], bfr[nn][1], acc[m][nn], 0, 0, 0);
      }
  }
  const int part = cbase / DM;      // uniform per block
  ushort_t* dst = (part == 0) ? Qo : ((part == 1) ? Ko : Vo);
  const float sc2 = (part == 0) ? SCALE : 1.0f;   // pre-scale Q
  #pragma unroll
  for (int nn = 0; nn < 4; ++nn) {
    const int h  = cbase - part*DM + wc*64 + nn*16;
    const int nh = h >> 6;
    const int d  = (h & 63) + lcol;
    #pragma unroll
    for (int m = 0; m < 4; ++m)
      #pragma unroll
      for (int reg = 0; reg < 4; ++reg) {
        const int r = rbase + wr*64 + m*16 + lrow*4 + reg;
        const int i = r >> 1, b = r & 1;
        dst[((size_t)(b*NH + nh)*QLEN + i)*DH + d] = f2bf(acc[m][nn][reg] * sc2);
      }
  }
}

// ---------------------------------------------------------------------------
// Kernel 2: V bf16 [bn][j][d] -> Vt bf16 [bn][d][j]  (LDS transpose)
// ---------------------------------------------------------------------------
__global__ __launch_bounds__(256)
void vt_pack(const ushort_t* __restrict__ V, ushort_t* __restrict__ Vt) {
  __shared__ ushort_t Ls[64][72];
  const int jt = blockIdx.x, bn = blockIdx.y;
  const int tid = threadIdx.x;
  const size_t base = (size_t)bn * (QLEN*DH);
  #pragma unroll
  for (int q = 0; q < 2; ++q) {
    const int row = (tid>>3) + 32*q;
    const int c8  = (tid&7)*8;
    *(short8*)&Ls[row][c8] = *(const short8*)&V[base + (size_t)(jt*64+row)*DH + c8];
  }
  __syncthreads();
  #pragma unroll
  for (int q = 0; q < 2; ++q) {
    const int d  = (tid>>3) + 32*q;
    const int j8 = (tid&7)*8;
    short8 o;
    #pragma unroll
    for (int e = 0; e < 8; ++e) o[e] = (short)Ls[j8+e][d];
    *(short8*)&Vt[base + (size_t)d*QLEN + jt*64 + j8] = o;
  }
}

// ---------------------------------------------------------------------------
// Kernel 3: pack r_emb -> RELp bf16 [n][g][d] (zero pad); rbias*SCALE -> rbp
// ---------------------------------------------------------------------------
__global__ __launch_bounds__(256)
void rel_pack(const float* __restrict__ remb, const float* __restrict__ rbias,
              ushort_t* __restrict__ RELp, float* __restrict__ rbp) {
  const int n = blockIdx.y;
  const int g = blockIdx.x*4 + (threadIdx.x >> 6);
  const int d = threadIdx.x & 63;
  const bool ok = g < QLEN;
  const float v = ok ? remb[((size_t)g*NH + n)*DH + d] : 0.f;
  RELp[((size_t)n*RELROWS + g)*DH + d] = f2bf(v);
  if (d == 0) rbp[n*RELROWS + g] = (ok ? rbias[g*NH + n] : 0.f) * SCALE;
}

// ---------------------------------------------------------------------------
// Kernel 4: KB[b,n,j] = dot(r_w_bias[n], K[b,n,j,:]) * SCALE
// ---------------------------------------------------------------------------
__global__ __launch_bounds__(256)
void kbias_kernel(const ushort_t* __restrict__ K, const float* __restrict__ rwb,
                  float* __restrict__ KB) {
  const int wv = threadIdx.x >> 6, lane = threadIdx.x & 63;
  const int row = blockIdx.x*4 + wv;             // (b*NH+n)*QLEN + j
  const int n = (row >> 11) % NH;
  float v = bf2f(K[(size_t)row*DH + lane]) * rwb[n*DH + lane];
  #pragma unroll
  for (int o = 32; o > 0; o >>= 1) v += __shfl_xor(v, o, 64);
  if (lane == 0) KB[row] = v * SCALE;
}

// ---------------------------------------------------------------------------
// Kernel 5: MFMA flash attention, KV-split partials.
// grid = (64 = 32 it-tiles x 2 kv-chunks [it reversed], 24 bn), block = 256.
// Wave w owns q-rows it*64 + w*16..+15.  Chunk c covers keys [c*1024,
// c*1024+1024) as <=8 iterations of 128 keys.  No block barriers: LDS is
// wave-private.  Q/KB/rbias pre-scaled by SCALE.  Invariant: j0 <= it*64 <=
// ib, so every row has >=1 real key per iteration and g in [0, 2176).
// Writes unnormalized partial (acc bf16, m/l f32) per (bn, it, c).
// ---------------------------------------------------------------------------
__global__ __launch_bounds__(256)
void attn_partial(const ushort_t* __restrict__ Qb,
                  const ushort_t* __restrict__ Kb,
                  const ushort_t* __restrict__ Vt,
                  const ushort_t* __restrict__ RELp,
                  const float* __restrict__ rbp,
                  const float* __restrict__ KB,
                  ushort_t* __restrict__ Pacc,
                  float* __restrict__ Pm,
                  float* __restrict__ Pl) {
  __shared__ __align__(16) ushort_t Tlds[4][16*PADT2];
  __shared__ __align__(16) ushort_t Plds[4][16*PADP];
  const int x  = blockIdx.x;
  const int it = 31 - (x >> 1);
  const int c  = x & 1;
  if (c == 1 && it < 16) return;
  const int bn = blockIdx.y;
  const int n  = bn % NH;
  const int tid = threadIdx.x;
  const int wv = tid >> 6, lane = tid & 63;
  const int lrow = lane >> 4, lcol = lane & 15;
  const int ib = it*64 + wv*16;
  const size_t base = (size_t)bn * (QLEN*DH);
  ushort_t* Tw = &Tlds[wv][0];
  ushort_t* Pw = &Plds[wv][0];

  const int qi = ib + lcol;
  const short8 qf0 = *(const short8*)&Qb[base + (size_t)qi*DH + lrow*8];
  const short8 qf1 = *(const short8*)&Qb[base + (size_t)qi*DH + 32 + lrow*8];

  f32x4 accO[4];
  float m[4], lsum[4];
  #pragma unroll
  for (int r = 0; r < 4; ++r) {
    accO[r] = (f32x4){0.f,0.f,0.f,0.f};
    m[r] = -3.0e38f; lsum[r] = 0.f;
  }

  const int klen = it*64 + 64;
  const int nits = min(8, (klen - c*1024 + 127) >> 7);
  for (int itr = 0; itr < nits; ++itr) {
    const int j0 = c*1024 + itr*128;
    const int gbase = 2032 + j0 - ib;
    // ---- T strip = Qs*REL^T + rbias (9 col-blocks) -> wave-private LDS ----
    #pragma unroll
    for (int cb = 0; cb < 9; ++cb) {
      const int g = gbase + cb*16 + lcol;               // in [0, 2176)
      const size_t ro = ((size_t)n*RELROWS + g)*DH + lrow*8;
      const short8 r0 = *(const short8*)&RELp[ro];
      const short8 r1 = *(const short8*)&RELp[ro + 32];
      f32x4 t = (f32x4){0.f,0.f,0.f,0.f};
      t = __builtin_amdgcn_mfma_f32_16x16x32_bf16(qf0, r0, t, 0, 0, 0);
      t = __builtin_amdgcn_mfma_f32_16x16x32_bf16(qf1, r1, t, 0, 0, 0);
      const float rb = rbp[n*RELROWS + g];
      #pragma unroll
      for (int reg = 0; reg < 4; ++reg)
        Tw[(lrow*4 + reg)*PADT2 + cb*16 + lcol] = f2bf(t[reg] + rb);
    }
    // ---- S = Qs * K^T (8 col-blocks = 128 keys) ----
    f32x4 s[8];
    #pragma unroll
    for (int cb = 0; cb < 8; ++cb) {
      const size_t ko = base + (size_t)(j0 + cb*16 + lcol)*DH + lrow*8;
      const short8 k0 = *(const short8*)&Kb[ko];
      const short8 k1 = *(const short8*)&Kb[ko + 32];
      f32x4 a = (f32x4){0.f,0.f,0.f,0.f};
      a = __builtin_amdgcn_mfma_f32_16x16x32_bf16(qf0, k0, a, 0, 0, 0);
      a = __builtin_amdgcn_mfma_f32_16x16x32_bf16(qf1, k1, a, 0, 0, 0);
      s[cb] = a;
    }
    // ---- combine terms + causal mask ----
    #pragma unroll
    for (int cb = 0; cb < 8; ++cb) {
      const int jg = j0 + cb*16 + lcol;
      const float kbv = KB[bn*QLEN + min(jg, QLEN-1)];
      #pragma unroll
      for (int reg = 0; reg < 4; ++reg) {
        const int row = lrow*4 + reg;
        const int ig  = ib + row;
        const int tc  = 15 + cb*16 + lcol - row;        // [0, 143]
        const float sv = s[cb][reg] + bf2f(Tw[row*PADT2 + tc]) + kbv;
        s[cb][reg] = (jg > ig) ? -3.0e38f : sv;
      }
    }
    // ---- online softmax over 128 keys ----
    #pragma unroll
    for (int reg = 0; reg < 4; ++reg) {
      float mx = s[0][reg];
      #pragma unroll
      for (int cb = 1; cb < 8; ++cb) mx = fmaxf(mx, s[cb][reg]);
      mx = fmaxf(mx, __shfl_xor(mx, 1, 64));
      mx = fmaxf(mx, __shfl_xor(mx, 2, 64));
      mx = fmaxf(mx, __shfl_xor(mx, 4, 64));
      mx = fmaxf(mx, __shfl_xor(mx, 8, 64));
      const float mn = fmaxf(m[reg], mx);
      const float al = __expf(m[reg] - mn);
      m[reg] = mn;
      float ps = 0.f;
      #pragma unroll
      for (int cb = 0; cb < 8; ++cb) {
        const float p = __expf(s[cb][reg] - mn);
        s[cb][reg] = p; ps += p;
      }
      ps += __shfl_xor(ps, 1, 64);
      ps += __shfl_xor(ps, 2, 64);
      ps += __shfl_xor(ps, 4, 64);
      ps += __shfl_xor(ps, 8, 64);
      lsum[reg] = lsum[reg]*al + ps;
      #pragma unroll
      for (int cb = 0; cb < 4; ++cb) accO[cb][reg] *= al;
      const int row = lrow*4 + reg;
      #pragma unroll
      for (int cb = 0; cb < 8; ++cb)
        Pw[row*PADP + cb*16 + lcol] = f2bf(s[cb][reg]);
    }
    // ---- O += P * V (4 k-slices of 32) ----
    short8 pa[4];
    #pragma unroll
    for (int ks = 0; ks < 4; ++ks)
      pa[ks] = *(const short8*)&Pw[lcol*PADP + ks*32 + lrow*8];
    #pragma unroll
    for (int cb = 0; cb < 4; ++cb) {
      #pragma unroll
      for (int ks = 0; ks < 4; ++ks) {
        const size_t vo = base + (size_t)(cb*16 + lcol)*QLEN + j0 + ks*32 + lrow*8;
        const short8 vf = *(const short8*)&Vt[vo];
        accO[cb] = __builtin_amdgcn_mfma_f32_16x16x32_bf16(pa[ks], vf, accO[cb], 0, 0, 0);
      }
    }
  }
  // ---- store partial ----
  const int slot = (bn*32 + it)*2 + c;
  #pragma unroll
  for (int reg = 0; reg < 4; ++reg) {
    const int row = wv*16 + lrow*4 + reg;
    #pragma unroll
    for (int cb = 0; cb < 4; ++cb)
      Pacc[(size_t)slot*4096 + row*64 + cb*16 + lcol] = f2bf(accO[cb][reg]);
    if (lcol == 0) { Pm[slot*64 + row] = m[reg]; Pl[slot*64 + row] = lsum[reg]; }
  }
}

// ---------------------------------------------------------------------------
// Kernel 5b: combine <=2 chunk partials per q-row, normalize, emit bf16 AV.
// ---------------------------------------------------------------------------
__global__ __launch_bounds__(256)
void attn_combine(const ushort_t* __restrict__ Pacc, const float* __restrict__ Pm,
                  const float* __restrict__ Pl, ushort_t* __restrict__ AV) {
  const int it = blockIdx.x, bn = blockIdx.y;
  const int tid = threadIdx.x;
  const int row = tid >> 2, d0 = (tid & 3) << 4;
  const int slot0 = (bn*32 + it)*2;
  float acc[16];
  {
    const short8 a0 = *(const short8*)&Pacc[(size_t)slot0*4096 + row*64 + d0];
    const short8 a1 = *(const short8*)&Pacc[(size_t)slot0*4096 + row*64 + d0 + 8];
    #pragma unroll
    for (int e = 0; e < 8; ++e) {
      acc[e]   = bf2f((ushort_t)a0[e]);
      acc[e+8] = bf2f((ushort_t)a1[e]);
    }
  }
  float lv;
  if (it >= 16) {
    const float m0 = Pm[slot0*64 + row], m1 = Pm[(slot0+1)*64 + row];
    const float l0 = Pl[slot0*64 + row], l1 = Pl[(slot0+1)*64 + row];
    const float ms = fmaxf(m0, m1);
    const float w0 = __expf(m0 - ms), w1 = __expf(m1 - ms);
    lv = l0*w0 + l1*w1;
    const short8 b0 = *(const short8*)&Pacc[(size_t)(slot0+1)*4096 + row*64 + d0];
    const short8 b1 = *(const short8*)&Pacc[(size_t)(slot0+1)*4096 + row*64 + d0 + 8];
    #pragma unroll
    for (int e = 0; e < 8; ++e) {
      acc[e]   = acc[e]*w0   + bf2f((ushort_t)b0[e])*w1;
      acc[e+8] = acc[e+8]*w0 + bf2f((ushort_t)b1[e])*w1;
    }
  } else {
    lv = Pl[slot0*64 + row];
  }
  const float inv = 1.0f / lv;
  const int i = it*64 + row;
  short8 o0, o1;
  #pragma unroll
  for (int e = 0; e < 8; ++e) {
    o0[e] = (short)f2bf(acc[e]*inv);
    o1[e] = (short)f2bf(acc[e+8]*inv);
  }
  *(short8*)&AV[((size_t)bn*QLEN + i)*DH + d0] = o0;
  *(short8*)&AV[((size_t)bn*QLEN + i)*DH + d0 + 8] = o1;
}

// ---------------------------------------------------------------------------
// Kernel 6: O-projection, bf16 MFMA.
// ---------------------------------------------------------------------------
__global__ __launch_bounds__(256)
void oproj_mfma(const ushort_t* __restrict__ AVp, const ushort_t* __restrict__ B,
                float* __restrict__ AO) {
  __shared__ __align__(16) ushort_t As[128*64];
  __shared__ __align__(16) ushort_t Bs[128*64];
  const int bx = blockIdx.x;        // 6 N-tiles
  const int by = blockIdx.y;        // 32 M-tiles
  const int rbase = by*128, cbase = bx*128;
  const int tid = threadIdx.x;
  const int wv = tid>>6, lane = tid&63, lrow = lane>>4, lcol = lane&15;
  const int wr = wv>>1, wc = wv&1;
  const int sr = tid>>3, sc = tid&7;

  f32x4 acc[4][4];
  #pragma unroll
  for (int m = 0; m < 4; ++m)
    #pragma unroll
    for (int nn = 0; nn < 4; ++nn)
      acc[m][nn] = (f32x4){0.f,0.f,0.f,0.f};

  for (int kk = 0; kk < DM; kk += 64) {
    const int nh = kk >> 6;         // head index
    __syncthreads();
    #pragma unroll
    for (int q = 0; q < 4; ++q) {
      const int row = sr + 32*q;
      const int r = rbase + row, i = r >> 1, b = r & 1;
      const short8 va = *(const short8*)&AVp[((size_t)(b*NH + nh)*QLEN + i)*DH + sc*8];
      *(short8*)((char*)As + row*128 + ((sc*16) ^ ((row&7)<<4))) = va;
      const short8 vb = *(const short8*)&B[(size_t)(cbase+row)*DM + kk + sc*8];
      *(short8*)((char*)Bs + row*128 + ((sc*16) ^ ((row&7)<<4))) = vb;
    }
    __syncthreads();
    short8 af[4][2], bfr[4][2];
    #pragma unroll
    for (int m = 0; m < 4; ++m) {
      const int row = wr*64 + m*16 + lcol;
      af[m][0] = *(const short8*)((const char*)As + row*128 + (((     lrow*16)) ^ ((row&7)<<4)));
      af[m][1] = *(const short8*)((const char*)As + row*128 + (((64 + lrow*16)) ^ ((row&7)<<4)));
    }
    #pragma unroll
    for (int nn = 0; nn < 4; ++nn) {
      const int row = wc*64 + nn*16 + lcol;
      bfr[nn][0] = *(const short8*)((const char*)Bs + row*128 + (((     lrow*16)) ^ ((row&7)<<4)));
      bfr[nn][1] = *(const short8*)((const char*)Bs + row*128 + (((64 + lrow*16)) ^ ((row&7)<<4)));
    }
    #pragma unroll
    for (int m = 0; m < 4; ++m)
      #pragma unroll
      for (int nn = 0; nn < 4; ++nn) {
        acc[m][nn] = __builtin_amdgcn_mfma_f32_16x16x32_bf16(af[m][0], bfr[nn][0], acc[m][nn], 0, 0, 0);
        acc[m][nn] = __builtin_amdgcn_mfma_f32_16x16x32_bf16(af[m][1], bfr[nn][1], acc[m][nn], 0, 0, 0);
      }
  }
  #pragma unroll
  for (int nn = 0; nn < 4; ++nn) {
    const int mcol = cbase + wc*64 + nn*16 + lcol;
    #pragma unroll
    for (int mi = 0; mi < 4; ++mi)
      #pragma unroll
      for (int reg = 0; reg < 4; ++reg) {
        const int r = rbase + wr*64 + mi*16 + lrow*4 + reg;
        AO[(size_t)r*DM + mcol] = acc[mi][nn][reg];
      }
  }
}

// ---------------------------------------------------------------------------
// Kernel 7: residual + LayerNorm.
// ---------------------------------------------------------------------------
__global__ __launch_bounds__(256)
void ln_kernel(const float* __restrict__ AO, const float* __restrict__ W,
               const float* __restrict__ gamma, const float* __restrict__ beta,
               float* __restrict__ out) {
  const int r = blockIdx.x;
  const int tid = threadIdx.x;
  const int wv = tid >> 6, lane = tid & 63;
  float x[3];
  #pragma unroll
  for (int q = 0; q < 3; ++q) {
    const int mcol = tid + q*256;
    x[q] = AO[(size_t)r*DM + mcol] + W[(size_t)r*DM + mcol];
  }
  float s1 = x[0] + x[1] + x[2];
  float s2 = x[0]*x[0] + x[1]*x[1] + x[2]*x[2];
  #pragma unroll
  for (int o = 32; o > 0; o >>= 1) { s1 += __shfl_xor(s1, o, 64); s2 += __shfl_xor(s2, o, 64); }
  __shared__ float a1[4], a2[4];
  if (lane == 0) { a1[wv] = s1; a2[wv] = s2; }
  __syncthreads();
  s1 = a1[0] + a1[1] + a1[2] + a1[3];
  s2 = a2[0] + a2[1] + a2[2] + a2[3];
  const float mu  = s1 * (1.0f/DM);
  const float var = s2 * (1.0f/DM) - mu*mu;
  const float rs  = rsqrtf(var + 1e-5f);
  #pragma unroll
  for (int q = 0; q < 3; ++q) {
    const int mcol = tid + q*256;
    out[(size_t)r*DM + mcol] = (x[q] - mu)*rs*gamma[mcol] + beta[mcol];
  }
}

// ---------------------------------------------------------------------------
extern "C" void kernel_launch(void* const* d_in, const int* in_sizes, int n_in,
                              void* d_out, int out_size, void* d_ws, size_t ws_size,
                              hipStream_t stream) {
  const float* w      = (const float*)d_in[0];
  const float* r_emb  = (const float*)d_in[1];
  const float* r_wb   = (const float*)d_in[2];
  const float* r_bias = (const float*)d_in[3];
  const float* qkv_w  = (const float*)d_in[4];
  const float* o_w    = (const float*)d_in[5];
  const float* ln_g   = (const float*)d_in[6];
  const float* ln_b   = (const float*)d_in[7];
  float* out = (float*)d_out;

  const size_t QS = (size_t)BSZ*NH*QLEN*DH;       // 3,145,728 elems
  ushort_t* u      = (ushort_t*)d_ws;
  ushort_t* wbf    = u;                           // QS       (dead after qkv_mfma)
  ushort_t* qkvwbf = wbf + QS;                    // HID*DM   (dead after qkv_mfma)
  ushort_t* Vb16   = qkvwbf + (size_t)HID*DM;     // QS       (dead after vt_pack)
  ushort_t* Qb     = Vb16 + QS;
  ushort_t* Kb     = Qb + QS;
  ushort_t* Vt     = Kb + QS;
  ushort_t* AVb16  = Vt + QS;
  ushort_t* owbf   = AVb16 + QS;                  // DM*DM
  ushort_t* RELp   = owbf + (size_t)DM*DM;        // NH*RELROWS*DH
  float* rbp = (float*)(RELp + (size_t)NH*RELROWS*DH);
  float* KBb = rbp + NH*RELROWS;
  // Partials overlay the dead wbf/qkvwbf/Vb16 region (16.1 MB >= 13.4 MB):
  ushort_t* Pacc = u;                             // 1536 slots * 4096 bf16
  float* Pmb = (float*)(u + (size_t)1536*4096);   // 1536*64 f32
  float* Plb = Pmb + 1536*64;                     // 1536*64 f32
  float* AO  = (float*)d_ws;                      // aliases Pacc (dead by oproj)

  pack_bf16<<<dim3(1536), dim3(256), 0, stream>>>(w, wbf, (int)(QS/8));
  pack_bf16<<<dim3(864),  dim3(256), 0, stream>>>(qkv_w, qkvwbf, HID*DM/8);
  pack_bf16<<<dim3(288),  dim3(256), 0, stream>>>(o_w, owbf, DM*DM/8);

  qkv_mfma<<<dim3(HID/128, (QLEN*BSZ)/128), dim3(256), 0, stream>>>(wbf, qkvwbf, Qb, Kb, Vb16);
  vt_pack<<<dim3(QLEN/64, BSZ*NH), dim3(256), 0, stream>>>(Vb16, Vt);
  rel_pack<<<dim3(RELROWS/4, NH), dim3(256), 0, stream>>>(r_emb, r_bias, RELp, rbp);
  kbias_kernel<<<dim3(BSZ*NH*QLEN/4), dim3(256), 0, stream>>>(Kb, r_wb, KBb);
  attn_partial<<<dim3(64, BSZ*NH), dim3(256), 0, stream>>>(Qb, Kb, Vt, RELp, rbp, KBb, Pacc, Pmb, Plb);
  attn_combine<<<dim3(32, BSZ*NH), dim3(256), 0, stream>>>(Pacc, Pmb, Plb, AVb16);
  oproj_mfma<<<dim3(DM/128, (QLEN*BSZ)/128), dim3(256), 0, stream>>>(AVb16, owbf, AO);
  ln_kernel<<<dim3(QLEN*BSZ), dim3(256), 0, stream>>>(AO, w, ln_g, ln_b, out);
}

// Round 5
// 309.040 us; speedup vs baseline: 12.3282x; 1.2874x over previous
//
#include <hip/hip_runtime.h>

#define QLEN 2048
#define BSZ  2
#define NH   12
#define DH   64
#define DM   768
#define HID  2304
#define SCALE 0.125f
#define RELROWS 2176     // 2048 + 128 zero pad
#define PADT2 152        // T strip row stride (bf16 elems)
#define PADP  136        // P tile row stride (bf16 elems)

typedef __attribute__((ext_vector_type(8))) short short8;
typedef __attribute__((ext_vector_type(4))) float f32x4;
typedef unsigned short ushort_t;

static __device__ __forceinline__ ushort_t f2bf(float x) {
  unsigned u = __float_as_uint(x);
  return (ushort_t)((u + 0x7FFFu + ((u >> 16) & 1u)) >> 16);
}
static __device__ __forceinline__ float bf2f(ushort_t h) {
  return __uint_as_float(((unsigned)h) << 16);
}

// ---------------------------------------------------------------------------
// Kernel 0: f32 -> bf16 pack (8 elements/thread)
// ---------------------------------------------------------------------------
__global__ __launch_bounds__(256)
void pack_bf16(const float* __restrict__ src, ushort_t* __restrict__ dst, int n8) {
  const int idx = blockIdx.x*256 + threadIdx.x;
  if (idx >= n8) return;
  const float4 a = *(const float4*)&src[(size_t)idx*8];
  const float4 b = *(const float4*)&src[(size_t)idx*8 + 4];
  short8 o;
  o[0]=(short)f2bf(a.x); o[1]=(short)f2bf(a.y); o[2]=(short)f2bf(a.z); o[3]=(short)f2bf(a.w);
  o[4]=(short)f2bf(b.x); o[5]=(short)f2bf(b.y); o[6]=(short)f2bf(b.z); o[7]=(short)f2bf(b.w);
  *(short8*)&dst[(size_t)idx*8] = o;
}

// ---------------------------------------------------------------------------
// Kernel 1: QKV projection, bf16 MFMA.  Q part pre-scaled by SCALE.
// ---------------------------------------------------------------------------
__global__ __launch_bounds__(256)
void qkv_mfma(const ushort_t* __restrict__ A, const ushort_t* __restrict__ B,
              ushort_t* __restrict__ Qo, ushort_t* __restrict__ Ko,
              ushort_t* __restrict__ Vo) {
  __shared__ __align__(16) ushort_t As[128*64];
  __shared__ __align__(16) ushort_t Bs[128*64];
  const int bx = blockIdx.x;        // 18 N-tiles
  const int by = blockIdx.y;        // 32 M-tiles
  const int rbase = by*128, cbase = bx*128;
  const int tid = threadIdx.x;
  const int wv = tid>>6, lane = tid&63, lrow = lane>>4, lcol = lane&15;
  const int wr = wv>>1, wc = wv&1;
  const int sr = tid>>3, sc = tid&7;

  f32x4 acc[4][4];
  #pragma unroll
  for (int m = 0; m < 4; ++m)
    #pragma unroll
    for (int nn = 0; nn < 4; ++nn)
      acc[m][nn] = (f32x4){0.f,0.f,0.f,0.f};

  for (int kk = 0; kk < DM; kk += 64) {
    __syncthreads();
    #pragma unroll
    for (int q = 0; q < 4; ++q) {
      const int row = sr + 32*q;
      const short8 va = *(const short8*)&A[(size_t)(rbase+row)*DM + kk + sc*8];
      *(short8*)((char*)As + row*128 + ((sc*16) ^ ((row&7)<<4))) = va;
      const short8 vb = *(const short8*)&B[(size_t)(cbase+row)*DM + kk + sc*8];
      *(short8*)((char*)Bs + row*128 + ((sc*16) ^ ((row&7)<<4))) = vb;
    }
    __syncthreads();
    short8 af[4][2], bfr[4][2];
    #pragma unroll
    for (int m = 0; m < 4; ++m) {
      const int row = wr*64 + m*16 + lcol;
      af[m][0] = *(const short8*)((const char*)As + row*128 + (((     lrow*16)) ^ ((row&7)<<4)));
      af[m][1] = *(const short8*)((const char*)As + row*128 + (((64 + lrow*16)) ^ ((row&7)<<4)));
    }
    #pragma unroll
    for (int nn = 0; nn < 4; ++nn) {
      const int row = wc*64 + nn*16 + lcol;
      bfr[nn][0] = *(const short8*)((const char*)Bs + row*128 + (((     lrow*16)) ^ ((row&7)<<4)));
      bfr[nn][1] = *(const short8*)((const char*)Bs + row*128 + (((64 + lrow*16)) ^ ((row&7)<<4)));
    }
    #pragma unroll
    for (int m = 0; m < 4; ++m)
      #pragma unroll
      for (int nn = 0; nn < 4; ++nn) {
        acc[m][nn] = __builtin_amdgcn_mfma_f32_16x16x32_bf16(af[m][0], bfr[nn][0], acc[m][nn], 0, 0, 0);
        acc[m][nn] = __builtin_amdgcn_mfma_f32_16x16x32_bf16(af[m][1], bfr[nn][1], acc[m][nn], 0, 0, 0);
      }
  }
  const int part = cbase / DM;      // uniform per block
  ushort_t* dst = (part == 0) ? Qo : ((part == 1) ? Ko : Vo);
  const float sc2 = (part == 0) ? SCALE : 1.0f;   // pre-scale Q
  #pragma unroll
  for (int nn = 0; nn < 4; ++nn) {
    const int h  = cbase - part*DM + wc*64 + nn*16;
    const int nh = h >> 6;
    const int d  = (h & 63) + lcol;
    #pragma unroll
    for (int m = 0; m < 4; ++m)
      #pragma unroll
      for (int reg = 0; reg < 4; ++reg) {
        const int r = rbase + wr*64 + m*16 + lrow*4 + reg;
        const int i = r >> 1, b = r & 1;
        dst[((size_t)(b*NH + nh)*QLEN + i)*DH + d] = f2bf(acc[m][nn][reg] * sc2);
      }
  }
}

// ---------------------------------------------------------------------------
// Kernel 2: V bf16 [bn][j][d] -> Vt bf16 [bn][d][j]  (LDS transpose)
// ---------------------------------------------------------------------------
__global__ __launch_bounds__(256)
void vt_pack(const ushort_t* __restrict__ V, ushort_t* __restrict__ Vt) {
  __shared__ ushort_t Ls[64][72];
  const int jt = blockIdx.x, bn = blockIdx.y;
  const int tid = threadIdx.x;
  const size_t base = (size_t)bn * (QLEN*DH);
  #pragma unroll
  for (int q = 0; q < 2; ++q) {
    const int row = (tid>>3) + 32*q;
    const int c8  = (tid&7)*8;
    *(short8*)&Ls[row][c8] = *(const short8*)&V[base + (size_t)(jt*64+row)*DH + c8];
  }
  __syncthreads();
  #pragma unroll
  for (int q = 0; q < 2; ++q) {
    const int d  = (tid>>3) + 32*q;
    const int j8 = (tid&7)*8;
    short8 o;
    #pragma unroll
    for (int e = 0; e < 8; ++e) o[e] = (short)Ls[j8+e][d];
    *(short8*)&Vt[base + (size_t)d*QLEN + jt*64 + j8] = o;
  }
}

// ---------------------------------------------------------------------------
// Kernel 3: pack r_emb -> RELp bf16 [n][g][d] (zero pad); rbias*SCALE -> rbp
// ---------------------------------------------------------------------------
__global__ __launch_bounds__(256)
void rel_pack(const float* __restrict__ remb, const float* __restrict__ rbias,
              ushort_t* __restrict__ RELp, float* __restrict__ rbp) {
  const int n = blockIdx.y;
  const int g = blockIdx.x*4 + (threadIdx.x >> 6);
  const int d = threadIdx.x & 63;
  const bool ok = g < QLEN;
  const float v = ok ? remb[((size_t)g*NH + n)*DH + d] : 0.f;
  RELp[((size_t)n*RELROWS + g)*DH + d] = f2bf(v);
  if (d == 0) rbp[n*RELROWS + g] = (ok ? rbias[g*NH + n] : 0.f) * SCALE;
}

// ---------------------------------------------------------------------------
// Kernel 4: KB[b,n,j] = dot(r_w_bias[n], K[b,n,j,:]) * SCALE
// ---------------------------------------------------------------------------
__global__ __launch_bounds__(256)
void kbias_kernel(const ushort_t* __restrict__ K, const float* __restrict__ rwb,
                  float* __restrict__ KB) {
  const int wv = threadIdx.x >> 6, lane = threadIdx.x & 63;
  const int row = blockIdx.x*4 + wv;             // (b*NH+n)*QLEN + j
  const int n = (row >> 11) % NH;
  float v = bf2f(K[(size_t)row*DH + lane]) * rwb[n*DH + lane];
  #pragma unroll
  for (int o = 32; o > 0; o >>= 1) v += __shfl_xor(v, o, 64);
  if (lane == 0) KB[row] = v * SCALE;
}

// ---------------------------------------------------------------------------
// Kernel 5: MFMA flash attention, flat work decomposition.
// grid = (128 q-tiles of 16 rows [reversed], 24 bn), block = 512 (8 waves).
// All 8 waves share the SAME 16 q-rows; wave w handles key-tiles t = w, w+8
// (128 keys each).  NT = it16/8+1 <= 16  =>  every wave does <= 2 iterations
// (perfectly flat load).  No barriers in k-loop (LDS wave-private); partials
// (m, l, acc) merged across waves in LDS at the end (2 barriers total).
// Invariants: j0 = t*128 <= ib = it16*16, so g = 2032+j0-ib+[0,143] is in
// [0,2176), and jg = j0+[0,127] <= 2047.
// ---------------------------------------------------------------------------
#define TW_BYTES (16*PADT2*2)      // 4864 per wave
#define PW_BYTES (16*PADP*2)       // 4352 per wave
#define SMEM_BYTES (8*TW_BYTES + 8*PW_BYTES)   // 73728

__global__ __launch_bounds__(512, 4)
void attn_kernel(const ushort_t* __restrict__ Qb,
                 const ushort_t* __restrict__ Kb,
                 const ushort_t* __restrict__ Vt,
                 const ushort_t* __restrict__ RELp,
                 const float* __restrict__ rbp,
                 const float* __restrict__ KB,
                 ushort_t* __restrict__ AV) {
  __shared__ __align__(16) char smem[SMEM_BYTES];
  const int it16 = 127 - blockIdx.x;      // heavy tiles dispatch first
  const int bn   = blockIdx.y;
  const int n    = bn % NH;
  const int tid  = threadIdx.x;
  const int wv = tid >> 6, lane = tid & 63;
  const int lrow = lane >> 4, lcol = lane & 15;
  const int ib = it16*16;
  const size_t base = (size_t)bn * (QLEN*DH);
  ushort_t* Tw = (ushort_t*)(smem + wv*TW_BYTES);
  ushort_t* Pw = (ushort_t*)(smem + 8*TW_BYTES + wv*PW_BYTES);

  const int qi = ib + lcol;
  const short8 qf0 = *(const short8*)&Qb[base + (size_t)qi*DH + lrow*8];
  const short8 qf1 = *(const short8*)&Qb[base + (size_t)qi*DH + 32 + lrow*8];

  f32x4 accO[4];
  float m[4], lsum[4];
  #pragma unroll
  for (int r = 0; r < 4; ++r) {
    accO[r] = (f32x4){0.f,0.f,0.f,0.f};
    m[r] = -3.0e38f; lsum[r] = 0.f;
  }

  const int NT = (it16 >> 3) + 1;         // ceil((it16+1)*16/128)
  for (int t = wv; t < NT; t += 8) {
    const int j0 = t*128;
    const int gbase = 2032 + j0 - ib;
    // ---- T strip = Qs*REL^T + rbias (9 col-blocks) -> wave-private LDS ----
    #pragma unroll
    for (int cb = 0; cb < 9; ++cb) {
      const int g = gbase + cb*16 + lcol;               // in [0, 2176)
      const size_t ro = ((size_t)n*RELROWS + g)*DH + lrow*8;
      const short8 r0 = *(const short8*)&RELp[ro];
      const short8 r1 = *(const short8*)&RELp[ro + 32];
      f32x4 tt = (f32x4){0.f,0.f,0.f,0.f};
      tt = __builtin_amdgcn_mfma_f32_16x16x32_bf16(qf0, r0, tt, 0, 0, 0);
      tt = __builtin_amdgcn_mfma_f32_16x16x32_bf16(qf1, r1, tt, 0, 0, 0);
      const float rb = rbp[n*RELROWS + g];
      #pragma unroll
      for (int reg = 0; reg < 4; ++reg)
        Tw[(lrow*4 + reg)*PADT2 + cb*16 + lcol] = f2bf(tt[reg] + rb);
    }
    // ---- S = Qs * K^T (8 col-blocks = 128 keys) ----
    f32x4 s[8];
    #pragma unroll
    for (int cb = 0; cb < 8; ++cb) {
      const size_t ko = base + (size_t)(j0 + cb*16 + lcol)*DH + lrow*8;
      const short8 k0 = *(const short8*)&Kb[ko];
      const short8 k1 = *(const short8*)&Kb[ko + 32];
      f32x4 a = (f32x4){0.f,0.f,0.f,0.f};
      a = __builtin_amdgcn_mfma_f32_16x16x32_bf16(qf0, k0, a, 0, 0, 0);
      a = __builtin_amdgcn_mfma_f32_16x16x32_bf16(qf1, k1, a, 0, 0, 0);
      s[cb] = a;
    }
    // ---- combine terms + causal mask ----
    #pragma unroll
    for (int cb = 0; cb < 8; ++cb) {
      const int jg = j0 + cb*16 + lcol;                 // <= 2047
      const float kbv = KB[bn*QLEN + jg];
      #pragma unroll
      for (int reg = 0; reg < 4; ++reg) {
        const int row = lrow*4 + reg;
        const int ig  = ib + row;
        const int tc  = 15 + cb*16 + lcol - row;        // [0, 143]
        const float sv = s[cb][reg] + bf2f(Tw[row*PADT2 + tc]) + kbv;
        s[cb][reg] = (jg > ig) ? -3.0e38f : sv;
      }
    }
    // ---- online softmax over 128 keys ----
    #pragma unroll
    for (int reg = 0; reg < 4; ++reg) {
      float mx = s[0][reg];
      #pragma unroll
      for (int cb = 1; cb < 8; ++cb) mx = fmaxf(mx, s[cb][reg]);
      mx = fmaxf(mx, __shfl_xor(mx, 1, 64));
      mx = fmaxf(mx, __shfl_xor(mx, 2, 64));
      mx = fmaxf(mx, __shfl_xor(mx, 4, 64));
      mx = fmaxf(mx, __shfl_xor(mx, 8, 64));
      const float mn = fmaxf(m[reg], mx);
      const float al = __expf(m[reg] - mn);
      m[reg] = mn;
      float ps = 0.f;
      #pragma unroll
      for (int cb = 0; cb < 8; ++cb) {
        const float p = __expf(s[cb][reg] - mn);
        s[cb][reg] = p; ps += p;
      }
      ps += __shfl_xor(ps, 1, 64);
      ps += __shfl_xor(ps, 2, 64);
      ps += __shfl_xor(ps, 4, 64);
      ps += __shfl_xor(ps, 8, 64);
      lsum[reg] = lsum[reg]*al + ps;
      #pragma unroll
      for (int cb = 0; cb < 4; ++cb) accO[cb][reg] *= al;
      const int row = lrow*4 + reg;
      #pragma unroll
      for (int cb = 0; cb < 8; ++cb)
        Pw[row*PADP + cb*16 + lcol] = f2bf(s[cb][reg]);
    }
    // ---- O += P * V (4 k-slices of 32) ----
    short8 pa[4];
    #pragma unroll
    for (int ks = 0; ks < 4; ++ks)
      pa[ks] = *(const short8*)&Pw[lcol*PADP + ks*32 + lrow*8];
    #pragma unroll
    for (int cb = 0; cb < 4; ++cb) {
      #pragma unroll
      for (int ks = 0; ks < 4; ++ks) {
        const size_t vo = base + (size_t)(cb*16 + lcol)*QLEN + j0 + ks*32 + lrow*8;
        const short8 vf = *(const short8*)&Vt[vo];
        accO[cb] = __builtin_amdgcn_mfma_f32_16x16x32_bf16(pa[ks], vf, accO[cb], 0, 0, 0);
      }
    }
  }
  // ---- cross-wave merge in LDS ----
  __syncthreads();                                   // all waves done with T/P
  float* Macc = (float*)smem;                        // [8*16][68]
  float* Mm   = (float*)(smem + 128*68*4);           // [128]
  float* Ml   = Mm + 128;
  #pragma unroll
  for (int reg = 0; reg < 4; ++reg) {
    const int row = wv*16 + lrow*4 + reg;
    #pragma unroll
    for (int cb = 0; cb < 4; ++cb)
      Macc[row*68 + cb*16 + lcol] = accO[cb][reg];
    if (lcol == 0) { Mm[row] = m[reg]; Ml[row] = lsum[reg]; }
  }
  __syncthreads();
  #pragma unroll
  for (int h = 0; h < 2; ++h) {
    const int o = tid + h*512;
    const int row = o >> 6, col = o & 63;
    float M = Mm[row];
    #pragma unroll
    for (int w2 = 1; w2 < 8; ++w2) M = fmaxf(M, Mm[w2*16 + row]);
    float L = 0.f, V = 0.f;
    #pragma unroll
    for (int w2 = 0; w2 < 8; ++w2) {
      const float e = __expf(Mm[w2*16 + row] - M);
      L += Ml[w2*16 + row] * e;
      V += Macc[(w2*16 + row)*68 + col] * e;
    }
    AV[base + (size_t)(ib + row)*DH + col] = f2bf(V / L);
  }
}

// ---------------------------------------------------------------------------
// Kernel 6: O-projection, bf16 MFMA.
// ---------------------------------------------------------------------------
__global__ __launch_bounds__(256)
void oproj_mfma(const ushort_t* __restrict__ AVp, const ushort_t* __restrict__ B,
                float* __restrict__ AO) {
  __shared__ __align__(16) ushort_t As[128*64];
  __shared__ __align__(16) ushort_t Bs[128*64];
  const int bx = blockIdx.x;        // 6 N-tiles
  const int by = blockIdx.y;        // 32 M-tiles
  const int rbase = by*128, cbase = bx*128;
  const int tid = threadIdx.x;
  const int wv = tid>>6, lane = tid&63, lrow = lane>>4, lcol = lane&15;
  const int wr = wv>>1, wc = wv&1;
  const int sr = tid>>3, sc = tid&7;

  f32x4 acc[4][4];
  #pragma unroll
  for (int m = 0; m < 4; ++m)
    #pragma unroll
    for (int nn = 0; nn < 4; ++nn)
      acc[m][nn] = (f32x4){0.f,0.f,0.f,0.f};

  for (int kk = 0; kk < DM; kk += 64) {
    const int nh = kk >> 6;         // head index
    __syncthreads();
    #pragma unroll
    for (int q = 0; q < 4; ++q) {
      const int row = sr + 32*q;
      const int r = rbase + row, i = r >> 1, b = r & 1;
      const short8 va = *(const short8*)&AVp[((size_t)(b*NH + nh)*QLEN + i)*DH + sc*8];
      *(short8*)((char*)As + row*128 + ((sc*16) ^ ((row&7)<<4))) = va;
      const short8 vb = *(const short8*)&B[(size_t)(cbase+row)*DM + kk + sc*8];
      *(short8*)((char*)Bs + row*128 + ((sc*16) ^ ((row&7)<<4))) = vb;
    }
    __syncthreads();
    short8 af[4][2], bfr[4][2];
    #pragma unroll
    for (int m = 0; m < 4; ++m) {
      const int row = wr*64 + m*16 + lcol;
      af[m][0] = *(const short8*)((const char*)As + row*128 + (((     lrow*16)) ^ ((row&7)<<4)));
      af[m][1] = *(const short8*)((const char*)As + row*128 + (((64 + lrow*16)) ^ ((row&7)<<4)));
    }
    #pragma unroll
    for (int nn = 0; nn < 4; ++nn) {
      const int row = wc*64 + nn*16 + lcol;
      bfr[nn][0] = *(const short8*)((const char*)Bs + row*128 + (((     lrow*16)) ^ ((row&7)<<4)));
      bfr[nn][1] = *(const short8*)((const char*)Bs + row*128 + (((64 + lrow*16)) ^ ((row&7)<<4)));
    }
    #pragma unroll
    for (int m = 0; m < 4; ++m)
      #pragma unroll
      for (int nn = 0; nn < 4; ++nn) {
        acc[m][nn] = __builtin_amdgcn_mfma_f32_16x16x32_bf16(af[m][0], bfr[nn][0], acc[m][nn], 0, 0, 0);
        acc[m][nn] = __builtin_amdgcn_mfma_f32_16x16x32_bf16(af[m][1], bfr[nn][1], acc[m][nn], 0, 0, 0);
      }
  }
  #pragma unroll
  for (int nn = 0; nn < 4; ++nn) {
    const int mcol = cbase + wc*64 + nn*16 + lcol;
    #pragma unroll
    for (int mi = 0; mi < 4; ++mi)
      #pragma unroll
      for (int reg = 0; reg < 4; ++reg) {
        const int r = rbase + wr*64 + mi*16 + lrow*4 + reg;
        AO[(size_t)r*DM + mcol] = acc[mi][nn][reg];
      }
  }
}

// ---------------------------------------------------------------------------
// Kernel 7: residual + LayerNorm.
// ---------------------------------------------------------------------------
__global__ __launch_bounds__(256)
void ln_kernel(const float* __restrict__ AO, const float* __restrict__ W,
               const float* __restrict__ gamma, const float* __restrict__ beta,
               float* __restrict__ out) {
  const int r = blockIdx.x;
  const int tid = threadIdx.x;
  const int wv = tid >> 6, lane = tid & 63;
  float x[3];
  #pragma unroll
  for (int q = 0; q < 3; ++q) {
    const int mcol = tid + q*256;
    x[q] = AO[(size_t)r*DM + mcol] + W[(size_t)r*DM + mcol];
  }
  float s1 = x[0] + x[1] + x[2];
  float s2 = x[0]*x[0] + x[1]*x[1] + x[2]*x[2];
  #pragma unroll
  for (int o = 32; o > 0; o >>= 1) { s1 += __shfl_xor(s1, o, 64); s2 += __shfl_xor(s2, o, 64); }
  __shared__ float a1[4], a2[4];
  if (lane == 0) { a1[wv] = s1; a2[wv] = s2; }
  __syncthreads();
  s1 = a1[0] + a1[1] + a1[2] + a1[3];
  s2 = a2[0] + a2[1] + a2[2] + a2[3];
  const float mu  = s1 * (1.0f/DM);
  const float var = s2 * (1.0f/DM) - mu*mu;
  const float rs  = rsqrtf(var + 1e-5f);
  #pragma unroll
  for (int q = 0; q < 3; ++q) {
    const int mcol = tid + q*256;
    out[(size_t)r*DM + mcol] = (x[q] - mu)*rs*gamma[mcol] + beta[mcol];
  }
}

// ---------------------------------------------------------------------------
extern "C" void kernel_launch(void* const* d_in, const int* in_sizes, int n_in,
                              void* d_out, int out_size, void* d_ws, size_t ws_size,
                              hipStream_t stream) {
  const float* w      = (const float*)d_in[0];
  const float* r_emb  = (const float*)d_in[1];
  const float* r_wb   = (const float*)d_in[2];
  const float* r_bias = (const float*)d_in[3];
  const float* qkv_w  = (const float*)d_in[4];
  const float* o_w    = (const float*)d_in[5];
  const float* ln_g   = (const float*)d_in[6];
  const float* ln_b   = (const float*)d_in[7];
  float* out = (float*)d_out;

  const size_t QS = (size_t)BSZ*NH*QLEN*DH;       // 3,145,728 elems
  ushort_t* u      = (ushort_t*)d_ws;
  ushort_t* wbf    = u;                           // QS       (dead after qkv_mfma)
  ushort_t* qkvwbf = wbf + QS;                    // HID*DM   (dead after qkv_mfma)
  ushort_t* Vb16   = qkvwbf + (size_t)HID*DM;     // QS       (dead after vt_pack)
  ushort_t* Qb     = Vb16 + QS;
  ushort_t* Kb     = Qb + QS;
  ushort_t* Vt     = Kb + QS;
  ushort_t* AVb16  = Vt + QS;
  ushort_t* owbf   = AVb16 + QS;                  // DM*DM
  ushort_t* RELp   = owbf + (size_t)DM*DM;        // NH*RELROWS*DH
  float* rbp = (float*)(RELp + (size_t)NH*RELROWS*DH);
  float* KBb = rbp + NH*RELROWS;
  float* AO  = (float*)d_ws;                      // aliases wbf/qkvwbf/Vb16 (dead by oproj)

  pack_bf16<<<dim3(1536), dim3(256), 0, stream>>>(w, wbf, (int)(QS/8));
  pack_bf16<<<dim3(864),  dim3(256), 0, stream>>>(qkv_w, qkvwbf, HID*DM/8);
  pack_bf16<<<dim3(288),  dim3(256), 0, stream>>>(o_w, owbf, DM*DM/8);

  qkv_mfma<<<dim3(HID/128, (QLEN*BSZ)/128), dim3(256), 0, stream>>>(wbf, qkvwbf, Qb, Kb, Vb16);
  vt_pack<<<dim3(QLEN/64, BSZ*NH), dim3(256), 0, stream>>>(Vb16, Vt);
  rel_pack<<<dim3(RELROWS/4, NH), dim3(256), 0, stream>>>(r_emb, r_bias, RELp, rbp);
  kbias_kernel<<<dim3(BSZ*NH*QLEN/4), dim3(256), 0, stream>>>(Kb, r_wb, KBb);
  attn_kernel<<<dim3(128, BSZ*NH), dim3(512), 0, stream>>>(Qb, Kb, Vt, RELp, rbp, KBb, AVb16);
  oproj_mfma<<<dim3(DM/128, (QLEN*BSZ)/128), dim3(256), 0, stream>>>(AVb16, owbf, AO);
  ln_kernel<<<dim3(QLEN*BSZ), dim3(256), 0, stream>>>(AO, w, ln_g, ln_b, out);
}